// Round 1
// baseline (1580.024 us; speedup 1.0000x reference)
//
#include <hip/hip_runtime.h>
#include <hip/hip_bf16.h>
#include <cstdint>

#define DIM_   1024
#define H_     16
#define DH_    64
#define INNER_ 1024
#define B_     2
#define I_     2048
#define J_     2048
#define SCALE_ 0.125f

using bf16x8 = __attribute__((ext_vector_type(8))) short;
using f32x4  = __attribute__((ext_vector_type(4))) float;

__device__ __forceinline__ unsigned short f2bf(float f) {
  unsigned int u = __float_as_uint(f);
  u = (u + 0x7FFFu + ((u >> 16) & 1u)) >> 16;
  return (unsigned short)u;
}
__device__ __forceinline__ float bf2f(unsigned short h) {
  return __uint_as_float(((unsigned int)h) << 16);
}

// ---------------- LayerNorm + cast to bf16 ----------------
__global__ __launch_bounds__(256) void ln_cast_kernel(
    const float* __restrict__ in, const float* __restrict__ g,
    const float* __restrict__ bb, unsigned short* __restrict__ out) {
  int row = blockIdx.x;
  int t = threadIdx.x;
  const float4* rp = (const float4*)(in + (size_t)row * DIM_);
  float4 v = rp[t];
  float s  = v.x + v.y + v.z + v.w;
  float ss = v.x * v.x + v.y * v.y + v.z * v.z + v.w * v.w;
  for (int o = 1; o < 64; o <<= 1) {
    s  += __shfl_xor(s, o, 64);
    ss += __shfl_xor(ss, o, 64);
  }
  __shared__ float ls[4], lss[4];
  int wave = t >> 6, lane = t & 63;
  if (lane == 0) { ls[wave] = s; lss[wave] = ss; }
  __syncthreads();
  s  = ls[0] + ls[1] + ls[2] + ls[3];
  ss = lss[0] + lss[1] + lss[2] + lss[3];
  float mu  = s * (1.0f / DIM_);
  float var = ss * (1.0f / DIM_) - mu * mu;
  float rstd = rsqrtf(var + 1e-5f);
  float4 gv = ((const float4*)g)[t];
  float4 bv = ((const float4*)bb)[t];
  ushort4 o4;
  o4.x = f2bf((v.x - mu) * rstd * gv.x + bv.x);
  o4.y = f2bf((v.y - mu) * rstd * gv.y + bv.y);
  o4.z = f2bf((v.z - mu) * rstd * gv.z + bv.z);
  o4.w = f2bf((v.w - mu) * rstd * gv.w + bv.w);
  ((ushort4*)(out + (size_t)row * DIM_))[t] = o4;
}

// ---------------- transpose + cast f32 -> bf16 ----------------
__global__ __launch_bounds__(256) void transpose_cast_f32(
    const float* __restrict__ in, unsigned short* __restrict__ out, int R, int C) {
  __shared__ float tile[32][33];
  int z = blockIdx.z;
  const float* ip = in + (size_t)z * R * C;
  unsigned short* op = out + (size_t)z * R * C;
  int c0 = blockIdx.x * 32, r0 = blockIdx.y * 32;
  int tx = threadIdx.x, ty = threadIdx.y;
  for (int k = 0; k < 4; k++)
    tile[ty * 4 + k][tx] = ip[(size_t)(r0 + ty * 4 + k) * C + c0 + tx];
  __syncthreads();
  for (int k = 0; k < 4; k++)
    op[(size_t)(c0 + ty * 4 + k) * R + r0 + tx] = f2bf(tile[tx][ty * 4 + k]);
}

// ---------------- transpose bf16 -> bf16 ----------------
__global__ __launch_bounds__(256) void transpose_bf16(
    const unsigned short* __restrict__ in, unsigned short* __restrict__ out, int R, int C) {
  __shared__ unsigned short tile[32][33];
  int z = blockIdx.z;
  const unsigned short* ip = in + (size_t)z * R * C;
  unsigned short* op = out + (size_t)z * R * C;
  int c0 = blockIdx.x * 32, r0 = blockIdx.y * 32;
  int tx = threadIdx.x, ty = threadIdx.y;
  for (int k = 0; k < 4; k++)
    tile[ty * 4 + k][tx] = ip[(size_t)(r0 + ty * 4 + k) * C + c0 + tx];
  __syncthreads();
  for (int k = 0; k < 4; k++)
    op[(size_t)(c0 + ty * 4 + k) * R + r0 + tx] = tile[tx][ty * 4 + k];
}

// ---------------- bf16 GEMM: C[M,N] = A[M,K] @ Bt[N,K]^T (+bias) ----------------
#define LDP 40
__global__ __launch_bounds__(256) void gemm_bt(
    const unsigned short* __restrict__ A, const unsigned short* __restrict__ Bt,
    const float* __restrict__ bias, void* __restrict__ Cout,
    int M, int N, int K, int c_f32) {
  __shared__ unsigned short As[128 * LDP];
  __shared__ unsigned short Bs[128 * LDP];
  int t = threadIdx.x;
  int lane = t & 63, wave = t >> 6;
  int m0 = blockIdx.y * 128, n0 = blockIdx.x * 128;
  int wm = (wave >> 1) * 64, wn = (wave & 1) * 64;
  int l15 = lane & 15, lk = lane >> 4;
  int lrow = t >> 2, lc8 = (t & 3) * 8;
  f32x4 acc[4][4] = {};

  for (int k0 = 0; k0 < K; k0 += 32) {
    *(bf16x8*)&As[lrow * LDP + lc8]        = *(const bf16x8*)&A[(size_t)(m0 + lrow) * K + k0 + lc8];
    *(bf16x8*)&As[(lrow + 64) * LDP + lc8] = *(const bf16x8*)&A[(size_t)(m0 + lrow + 64) * K + k0 + lc8];
    *(bf16x8*)&Bs[lrow * LDP + lc8]        = *(const bf16x8*)&Bt[(size_t)(n0 + lrow) * K + k0 + lc8];
    *(bf16x8*)&Bs[(lrow + 64) * LDP + lc8] = *(const bf16x8*)&Bt[(size_t)(n0 + lrow + 64) * K + k0 + lc8];
    __syncthreads();
    bf16x8 af[4], bfr[4];
#pragma unroll
    for (int mi = 0; mi < 4; mi++) af[mi]  = *(const bf16x8*)&As[(wm + mi * 16 + l15) * LDP + lk * 8];
#pragma unroll
    for (int ni = 0; ni < 4; ni++) bfr[ni] = *(const bf16x8*)&Bs[(wn + ni * 16 + l15) * LDP + lk * 8];
#pragma unroll
    for (int mi = 0; mi < 4; mi++)
#pragma unroll
      for (int ni = 0; ni < 4; ni++)
        acc[mi][ni] = __builtin_amdgcn_mfma_f32_16x16x32_bf16(af[mi], bfr[ni], acc[mi][ni], 0, 0, 0);
    __syncthreads();
  }
#pragma unroll
  for (int mi = 0; mi < 4; mi++)
#pragma unroll
    for (int ni = 0; ni < 4; ni++) {
      int col = n0 + wn + ni * 16 + l15;
      float bsv = bias ? bias[col] : 0.0f;
#pragma unroll
      for (int r = 0; r < 4; r++) {
        int row = m0 + wm + mi * 16 + lk * 4 + r;
        float val = acc[mi][ni][r] + bsv;
        if (c_f32) ((float*)Cout)[(size_t)row * N + col] = val;
        else ((unsigned short*)Cout)[(size_t)row * N + col] = f2bf(val);
      }
    }
}

// ---------------- stats: rsum[b,h,i] = sum_j exp(SCALE * dot(...)) ----------------
__global__ __launch_bounds__(256) void stats_kernel(
    const unsigned short* __restrict__ Q, const unsigned short* __restrict__ Kc,
    float* __restrict__ rsum, int NQ, int NK) {
  int b = blockIdx.z, h = blockIdx.y, i0 = blockIdx.x * 32;
  int t = threadIdx.x, lane = t & 63, wave = t >> 6;
  int l15 = lane & 15, lk = lane >> 4;
  const size_t qbase = ((size_t)b * NQ + i0) * INNER_ + h * DH_;
  bf16x8 af[2][2];
#pragma unroll
  for (int mi = 0; mi < 2; mi++)
#pragma unroll
    for (int ks = 0; ks < 2; ks++)
      af[mi][ks] = *(const bf16x8*)&Q[qbase + (size_t)(mi * 16 + l15) * INNER_ + ks * 32 + lk * 8];
  float racc[2][4] = {};
  for (int j0 = wave * 16; j0 < NK; j0 += 64) {
    const size_t kbase = ((size_t)b * NK + j0 + l15) * INNER_ + h * DH_ + lk * 8;
    bf16x8 b0 = *(const bf16x8*)&Kc[kbase];
    bf16x8 b1 = *(const bf16x8*)&Kc[kbase + 32];
#pragma unroll
    for (int mi = 0; mi < 2; mi++) {
      f32x4 acc = {};
      acc = __builtin_amdgcn_mfma_f32_16x16x32_bf16(af[mi][0], b0, acc, 0, 0, 0);
      acc = __builtin_amdgcn_mfma_f32_16x16x32_bf16(af[mi][1], b1, acc, 0, 0, 0);
#pragma unroll
      for (int r = 0; r < 4; r++) racc[mi][r] += __expf(acc[r] * SCALE_);
    }
  }
#pragma unroll
  for (int o = 1; o < 16; o <<= 1)
#pragma unroll
    for (int mi = 0; mi < 2; mi++)
#pragma unroll
      for (int r = 0; r < 4; r++) racc[mi][r] += __shfl_xor(racc[mi][r], o, 64);
  __shared__ float part[4][32];
  if (l15 == 0)
#pragma unroll
    for (int mi = 0; mi < 2; mi++)
#pragma unroll
      for (int r = 0; r < 4; r++) part[wave][mi * 16 + lk * 4 + r] = racc[mi][r];
  __syncthreads();
  if (t < 32)
    rsum[((size_t)b * H_ + h) * NQ + i0 + t] = part[0][t] + part[1][t] + part[2][t] + part[3][t];
}

// ---------------- fused attention: 16-i tile, 32-j iter, XCD-pinned ----------------
// Restructured for occupancy + cross-barrier load overlap:
//  - 16-i tiles -> 1024 blocks (grid n: combo=n&7 -> b=combo>>2, jc=combo&3;
//    round-robin block->XCD dispatch pins each (b,jc) K/V chunk to one XCD L2).
//  - 4 waves: phase1 wave=(jstrip=w&1, hg=w>>1) computes 16i x 16j sim for 8 h;
//    Pb is now cross-wave (barrier AFTER phase1, not after phase3) so phase3's
//    V loads + PV MFMAs overlap the NEXT iteration's Q/K loads (no barrier
//    between P3 and next P1; Ms reuse guarded by next bar1, Pb by bar2).
//  - acc shrinks to 16 regs (wave owns 4 g x 16i x 64d); freed VGPRs hold
//    hoisted Q frags for hh 0..3 (halves Q re-read traffic); hh 4..7 re-read
//    (qo hack keeps them un-hoisted to bound pressure).
//  - LDS 37.3 KB (Pb 16K + Ms 20.25K + rinv 1K) -> 4 blocks/CU LDS-wise;
//    launch_bounds(256,3) -> >=12 waves/CU (was 8).
#define MSROW 40                  // 32 j + pad; 80 B stride, 16B-aligned b128 reads
#define MSG   (16 * MSROW + 8)   // 648 shorts per g
__global__ __launch_bounds__(256, 3) void fused_attn_kernel(
    const unsigned short* __restrict__ Q, const unsigned short* __restrict__ Kc,
    const unsigned short* __restrict__ Vt, const float* __restrict__ rsum,
    const float* __restrict__ thw,
    float* __restrict__ p0, float* __restrict__ p1,
    float* __restrict__ p2, float* __restrict__ p3,
    int NQ, int NK, int CHUNK) {
  __shared__ unsigned short Pb[2 * 256 * 16];   // 16 KB, quarter per jstrip
  __shared__ unsigned short Ms[16 * MSG];       // 20.25 KB
  __shared__ float rinvS[256];                  // [h][i 16]
  int n = blockIdx.x;
  int combo = n & 7;
  int b = combo >> 2, jc = combo & 3;
  int i0 = (n >> 3) * 16;
  float* __restrict__ Op = (jc == 0) ? p0 : (jc == 1) ? p1 : (jc == 2) ? p2 : p3;
  int t = threadIdx.x, lane = t & 63, wave = t >> 6;
  int l15 = lane & 15, lk = lane >> 4;
  int jstrip = wave & 1, hg = wave >> 1;

  rinvS[t] = 1.0f / rsum[((size_t)b * H_ + (t >> 4)) * NQ + i0 + (t & 15)];

  // thw B-frag: lane (l15=g, lk): k=lk*8+e; h=(lk&1)*8+e; lk<2 -> hi, else residual
  bf16x8 tfrag;
  {
    int part = lk >> 1, hb = (lk & 1) * 8;
#pragma unroll
    for (int e = 0; e < 8; e++) {
      float a = thw[l15 * H_ + hb + e];
      unsigned short hi = f2bf(a);
      tfrag[e] = (short)(part == 0 ? hi : f2bf(a - bf2f(hi)));
    }
  }
  __syncthreads();

  const unsigned short* Qb0 = Q + ((size_t)b * NQ + i0 + l15) * INNER_;
  bf16x8 qpre[8];                 // hoisted Q frags for hh 0..3 (32 VGPR)
#pragma unroll
  for (int hh = 0; hh < 4; hh++) {
    int h = hg * 8 + hh;
    qpre[hh * 2]     = *(const bf16x8*)&Qb0[h * 64 + lk * 8];
    qpre[hh * 2 + 1] = *(const bf16x8*)&Qb0[h * 64 + 32 + lk * 8];
  }
  int qo = 0;
  asm volatile("" : "+v"(qo));  // defeat hoist of remaining Q loads
  const unsigned short* Qb = Qb0 + qo;
  unsigned short* pw = &Pb[jstrip * 256 * 16];
  f32x4 acc[16] = {};  // [gi*4 + nt]
  const int jbeg = jc * CHUNK;

  for (int js = 0; js < CHUNK; js += 32) {
    int j0 = jbeg + js;
    const unsigned short* Kb = Kc + ((size_t)b * NK + j0 + jstrip * 16 + l15) * INNER_;
    // ---- phase 1: sim + normalize -> P^T for this wave's (jstrip, 8 h) ----
    unsigned int stage[4][4];
#pragma unroll
    for (int hh = 0; hh < 8; hh++) {
      int h = hg * 8 + hh;
      bf16x8 qa0, qa1;
      if (hh < 4) { qa0 = qpre[hh * 2]; qa1 = qpre[hh * 2 + 1]; }
      else {
        qa0 = *(const bf16x8*)&Qb[h * 64 + lk * 8];
        qa1 = *(const bf16x8*)&Qb[h * 64 + 32 + lk * 8];
      }
      bf16x8 kb0 = *(const bf16x8*)&Kb[h * 64 + lk * 8];
      bf16x8 kb1 = *(const bf16x8*)&Kb[h * 64 + 32 + lk * 8];
      f32x4 s = {};
      s = __builtin_amdgcn_mfma_f32_16x16x32_bf16(qa0, kb0, s, 0, 0, 0);
      s = __builtin_amdgcn_mfma_f32_16x16x32_bf16(qa1, kb1, s, 0, 0, 0);
      f32x4 ri = *(const f32x4*)&rinvS[h * 16 + lk * 4];
#pragma unroll
      for (int r = 0; r < 4; r++) {
        float e = __expf(s[r] * SCALE_) * ri[r];
        unsigned int bv = f2bf(e);
        if (hh & 1) stage[r][hh >> 1] |= bv << 16;
        else        stage[r][hh >> 1] = bv;
      }
    }
#pragma unroll
    for (int r = 0; r < 4; r++) {
      int row = (lk * 4 + r) * 16 + l15;          // pos = i*16 + j
      int col = (hg * 8) ^ ((row & 1) << 3);      // xor-swizzle banks
      uint4 u = {stage[r][0], stage[r][1], stage[r][2], stage[r][3]};
      *(uint4*)&pw[row * 16 + col] = u;
    }
    __syncthreads();   // bar1: Pb halves from both hg waves complete
    // ---- phase 2: MFMA mix; wave w: quarter q=w&1, i-range (w>>1)*8..+8 ----
    {
      int q = wave & 1, pbase = (wave >> 1) * 8;
      const unsigned short* pr = &Pb[q * 256 * 16];
#pragma unroll
      for (int p8 = 0; p8 < 8; p8++) {
        int p = pbase + p8;                       // p = i (within 16)
        int row = p * 16 + l15;                   // l15 = j (within quarter)
        int col = ((lk & 1) << 3) ^ ((row & 1) << 3);
        bf16x8 af = *(const bf16x8*)&pr[row * 16 + col];
        f32x4 m = {};
        m = __builtin_amdgcn_mfma_f32_16x16x32_bf16(af, tfrag, m, 0, 0, 0);
        // D: col=l15 -> g; rows lk*4+r -> j = q*16 + lk*4 + r; i = p
        ushort4 o;
        o.x = f2bf(m[0]); o.y = f2bf(m[1]); o.z = f2bf(m[2]); o.w = f2bf(m[3]);
        *(ushort4*)&Ms[l15 * MSG + p * MSROW + q * 16 + lk * 4] = o;
      }
    }
    __syncthreads();   // bar2: Ms complete
    // ---- phase 3: PV (wave owns g = wave*4..+3); overlaps next P1 loads ----
#pragma unroll
    for (int gi = 0; gi < 4; gi++) {
      int g = wave * 4 + gi;
      bf16x8 ma = *(const bf16x8*)&Ms[g * MSG + l15 * MSROW + lk * 8];
#pragma unroll
      for (int nt = 0; nt < 4; nt++) {
        const size_t vb = ((size_t)b * INNER_ + g * 64 + nt * 16 + l15) * NK + j0 + lk * 8;
        bf16x8 v0 = *(const bf16x8*)&Vt[vb];
        acc[gi * 4 + nt] = __builtin_amdgcn_mfma_f32_16x16x32_bf16(ma, v0, acc[gi * 4 + nt], 0, 0, 0);
      }
    }
    // no barrier here: next P1 writes only Pb (its readers finished before
    // bar2); next Ms writes are fenced by next bar1.
  }
#pragma unroll
  for (int gi = 0; gi < 4; gi++)
#pragma unroll
    for (int nt = 0; nt < 4; nt++) {
      int col = (wave * 4 + gi) * 64 + nt * 16 + l15;
#pragma unroll
      for (int r = 0; r < 4; r++)
        Op[((size_t)b * NQ + i0 + lk * 4 + r) * INNER_ + col] = acc[gi * 4 + nt][r];
    }
}

// ---------------- reduce 4 partials + cast to bf16 ----------------
__global__ __launch_bounds__(256) void reduce_cast_kernel(
    const float* __restrict__ p0, const float* __restrict__ p1,
    const float* __restrict__ p2, const float* __restrict__ p3,
    unsigned short* __restrict__ out, int n4) {
  int idx = blockIdx.x * 256 + threadIdx.x;
  if (idx >= n4) return;
  float4 v = ((const float4*)p0)[idx];
  float4 w = ((const float4*)p1)[idx];
  float4 a = ((const float4*)p2)[idx];
  float4 c = ((const float4*)p3)[idx];
  v.x += w.x + a.x + c.x; v.y += w.y + a.y + c.y;
  v.z += w.z + a.z + c.z; v.w += w.w + a.w + c.w;
  ushort4 o;
  o.x = f2bf(v.x); o.y = f2bf(v.y); o.z = f2bf(v.z); o.w = f2bf(v.w);
  ((ushort4*)out)[idx] = o;
}

// ---------------- launch ----------------
extern "C" void kernel_launch(void* const* d_in, const int* in_sizes, int n_in,
                              void* d_out, int out_size, void* d_ws, size_t ws_size,
                              hipStream_t stream) {
  const float* x      = (const float*)d_in[0];
  const float* ctx    = (const float*)d_in[1];
  const float* ln_g   = (const float*)d_in[2];
  const float* ln_b   = (const float*)d_in[3];
  const float* cln_g  = (const float*)d_in[4];
  const float* cln_b  = (const float*)d_in[5];
  const float* W_qk   = (const float*)d_in[6];
  const float* W_cqk  = (const float*)d_in[7];
  const float* W_v    = (const float*)d_in[8];
  const float* W_cv   = (const float*)d_in[9];
  const float* W_out  = (const float*)d_in[10];
  const float* b_out  = (const float*)d_in[11];
  const float* W_cout = (const float*)d_in[12];
  const float* b_cout = (const float*)d_in[13];
  const float* th_w   = (const float*)d_in[14];
  const float* cth_w  = (const float*)d_in[15];

  char* w = (char*)d_ws;
  const size_t SZ_ROW = (size_t)B_ * I_ * DIM_ * 2;   // 8.39 MB
  const size_t SZ_W   = (size_t)DIM_ * INNER_ * 2;    // 2.1 MB
  unsigned short* xn    = (unsigned short*)w; w += SZ_ROW;  // p0 overlay later
  unsigned short* cn    = (unsigned short*)w; w += SZ_ROW;
  unsigned short* Wqkt  = (unsigned short*)w; w += SZ_W;
  unsigned short* Wcqkt = (unsigned short*)w; w += SZ_W;
  unsigned short* Wvt   = (unsigned short*)w; w += SZ_W;
  unsigned short* Wcvt  = (unsigned short*)w; w += SZ_W;
  unsigned short* Woutt = (unsigned short*)w; w += SZ_W;
  unsigned short* Wcoutt= (unsigned short*)w; w += SZ_W;
  unsigned short* qk    = (unsigned short*)w; w += SZ_ROW;
  unsigned short* ck    = (unsigned short*)w; w += SZ_ROW;
  unsigned short* vv    = (unsigned short*)w; w += SZ_ROW;  // p1 overlay later
  unsigned short* cv    = (unsigned short*)w; w += SZ_ROW;
  unsigned short* vT    = (unsigned short*)w; w += SZ_ROW;
  unsigned short* cvT   = (unsigned short*)w; w += SZ_ROW;
  float* rsum = (float*)w; w += (size_t)B_ * H_ * I_ * 4;
  float* csum = (float*)w; w += (size_t)B_ * H_ * J_ * 4;
  unsigned short* Oh1 = (unsigned short*)w; w += SZ_ROW;
  unsigned short* Oh2 = (unsigned short*)w; w += SZ_ROW;

  // 4 partial buffers (16.78 MB each): p0 over xn+cn (dead after input GEMMs),
  // p1 over vv+cv (dead after transposes), p2/p3 fresh tail (fits: verified r2).
  const size_t PART = (size_t)B_ * I_ * INNER_ * 4;
  float* p0 = (float*)xn;
  float* p1 = (float*)vv;
  float* p2 = (float*)w;
  float* p3 = (float*)(w + PART);

  dim3 tb(32, 8);
  ln_cast_kernel<<<B_ * I_, 256, 0, stream>>>(x, ln_g, ln_b, xn);
  ln_cast_kernel<<<B_ * J_, 256, 0, stream>>>(ctx, cln_g, cln_b, cn);

  transpose_cast_f32<<<dim3(32, 32, 1), tb, 0, stream>>>(W_qk,   Wqkt,  DIM_, INNER_);
  transpose_cast_f32<<<dim3(32, 32, 1), tb, 0, stream>>>(W_cqk,  Wcqkt, DIM_, INNER_);
  transpose_cast_f32<<<dim3(32, 32, 1), tb, 0, stream>>>(W_v,    Wvt,   DIM_, INNER_);
  transpose_cast_f32<<<dim3(32, 32, 1), tb, 0, stream>>>(W_cv,   Wcvt,  DIM_, INNER_);
  transpose_cast_f32<<<dim3(32, 32, 1), tb, 0, stream>>>(W_out,  Woutt, INNER_, DIM_);
  transpose_cast_f32<<<dim3(32, 32, 1), tb, 0, stream>>>(W_cout, Wcoutt,INNER_, DIM_);

  gemm_bt<<<dim3(INNER_ / 128, (B_ * I_) / 128), 256, 0, stream>>>(xn, Wqkt,  nullptr, qk, B_ * I_, INNER_, DIM_, 0);
  gemm_bt<<<dim3(INNER_ / 128, (B_ * J_) / 128), 256, 0, stream>>>(cn, Wcqkt, nullptr, ck, B_ * J_, INNER_, DIM_, 0);
  gemm_bt<<<dim3(INNER_ / 128, (B_ * I_) / 128), 256, 0, stream>>>(xn, Wvt,   nullptr, vv, B_ * I_, INNER_, DIM_, 0);
  gemm_bt<<<dim3(INNER_ / 128, (B_ * J_) / 128), 256, 0, stream>>>(cn, Wcvt,  nullptr, cv, B_ * J_, INNER_, DIM_, 0);

  transpose_bf16<<<dim3(INNER_ / 32, I_ / 32, B_), tb, 0, stream>>>(vv, vT, I_, INNER_);
  transpose_bf16<<<dim3(INNER_ / 32, J_ / 32, B_), tb, 0, stream>>>(cv, cvT, J_, INNER_);

  stats_kernel<<<dim3(I_ / 32, H_, B_), 256, 0, stream>>>(qk, ck, rsum, I_, J_);
  stats_kernel<<<dim3(J_ / 32, H_, B_), 256, 0, stream>>>(ck, qk, csum, J_, I_);

  const int n4 = (B_ * I_ * INNER_) / 4;
  // dir1: softmax over j, rows i
  fused_attn_kernel<<<(I_ / 16) * 4 * B_, 256, 0, stream>>>(
      qk, ck, cvT, rsum, th_w, p0, p1, p2, p3, I_, J_, J_ / 4);
  reduce_cast_kernel<<<n4 / 256, 256, 0, stream>>>(p0, p1, p2, p3, Oh1, n4);
  // dir2: softmax over i, rows j
  fused_attn_kernel<<<(J_ / 16) * 4 * B_, 256, 0, stream>>>(
      ck, qk, vT, csum, cth_w, p0, p1, p2, p3, J_, I_, I_ / 4);
  reduce_cast_kernel<<<n4 / 256, 256, 0, stream>>>(p0, p1, p2, p3, Oh2, n4);

  gemm_bt<<<dim3(DIM_ / 128, (B_ * I_) / 128), 256, 0, stream>>>(Oh1, Woutt, b_out, (float*)d_out, B_ * I_, DIM_, INNER_, 1);
  gemm_bt<<<dim3(DIM_ / 128, (B_ * J_) / 128), 256, 0, stream>>>(Oh2, Wcoutt, b_cout, ((float*)d_out) + (size_t)B_ * I_ * DIM_, B_ * J_, DIM_, INNER_, 1);
}

// Round 2
// 924.698 us; speedup vs baseline: 1.7087x; 1.7087x over previous
//
#include <hip/hip_runtime.h>
#include <hip/hip_bf16.h>
#include <cstdint>

#define DIM_   1024
#define H_     16
#define DH_    64
#define INNER_ 1024
#define B_     2
#define I_     2048
#define J_     2048
#define SCALE_ 0.125f

using bf16x8 = __attribute__((ext_vector_type(8))) short;
using f32x4  = __attribute__((ext_vector_type(4))) float;

__device__ __forceinline__ unsigned short f2bf(float f) {
  unsigned int u = __float_as_uint(f);
  u = (u + 0x7FFFu + ((u >> 16) & 1u)) >> 16;
  return (unsigned short)u;
}
__device__ __forceinline__ float bf2f(unsigned short h) {
  return __uint_as_float(((unsigned int)h) << 16);
}

// ---------------- LayerNorm + cast to bf16 ----------------
__global__ __launch_bounds__(256) void ln_cast_kernel(
    const float* __restrict__ in, const float* __restrict__ g,
    const float* __restrict__ bb, unsigned short* __restrict__ out) {
  int row = blockIdx.x;
  int t = threadIdx.x;
  const float4* rp = (const float4*)(in + (size_t)row * DIM_);
  float4 v = rp[t];
  float s  = v.x + v.y + v.z + v.w;
  float ss = v.x * v.x + v.y * v.y + v.z * v.z + v.w * v.w;
  for (int o = 1; o < 64; o <<= 1) {
    s  += __shfl_xor(s, o, 64);
    ss += __shfl_xor(ss, o, 64);
  }
  __shared__ float ls[4], lss[4];
  int wave = t >> 6, lane = t & 63;
  if (lane == 0) { ls[wave] = s; lss[wave] = ss; }
  __syncthreads();
  s  = ls[0] + ls[1] + ls[2] + ls[3];
  ss = lss[0] + lss[1] + lss[2] + lss[3];
  float mu  = s * (1.0f / DIM_);
  float var = ss * (1.0f / DIM_) - mu * mu;
  float rstd = rsqrtf(var + 1e-5f);
  float4 gv = ((const float4*)g)[t];
  float4 bv = ((const float4*)bb)[t];
  ushort4 o4;
  o4.x = f2bf((v.x - mu) * rstd * gv.x + bv.x);
  o4.y = f2bf((v.y - mu) * rstd * gv.y + bv.y);
  o4.z = f2bf((v.z - mu) * rstd * gv.z + bv.z);
  o4.w = f2bf((v.w - mu) * rstd * gv.w + bv.w);
  ((ushort4*)(out + (size_t)row * DIM_))[t] = o4;
}

// ---------------- transpose + cast f32 -> bf16 ----------------
__global__ __launch_bounds__(256) void transpose_cast_f32(
    const float* __restrict__ in, unsigned short* __restrict__ out, int R, int C) {
  __shared__ float tile[32][33];
  int z = blockIdx.z;
  const float* ip = in + (size_t)z * R * C;
  unsigned short* op = out + (size_t)z * R * C;
  int c0 = blockIdx.x * 32, r0 = blockIdx.y * 32;
  int tx = threadIdx.x, ty = threadIdx.y;
  for (int k = 0; k < 4; k++)
    tile[ty * 4 + k][tx] = ip[(size_t)(r0 + ty * 4 + k) * C + c0 + tx];
  __syncthreads();
  for (int k = 0; k < 4; k++)
    op[(size_t)(c0 + ty * 4 + k) * R + r0 + tx] = f2bf(tile[tx][ty * 4 + k]);
}

// ---------------- transpose bf16 -> bf16 ----------------
__global__ __launch_bounds__(256) void transpose_bf16(
    const unsigned short* __restrict__ in, unsigned short* __restrict__ out, int R, int C) {
  __shared__ unsigned short tile[32][33];
  int z = blockIdx.z;
  const unsigned short* ip = in + (size_t)z * R * C;
  unsigned short* op = out + (size_t)z * R * C;
  int c0 = blockIdx.x * 32, r0 = blockIdx.y * 32;
  int tx = threadIdx.x, ty = threadIdx.y;
  for (int k = 0; k < 4; k++)
    tile[ty * 4 + k][tx] = ip[(size_t)(r0 + ty * 4 + k) * C + c0 + tx];
  __syncthreads();
  for (int k = 0; k < 4; k++)
    op[(size_t)(c0 + ty * 4 + k) * R + r0 + tx] = tile[tx][ty * 4 + k];
}

// ---------------- bf16 GEMM: C[M,N] = A[M,K] @ Bt[N,K]^T (+bias) ----------------
#define LDP 40
__global__ __launch_bounds__(256) void gemm_bt(
    const unsigned short* __restrict__ A, const unsigned short* __restrict__ Bt,
    const float* __restrict__ bias, void* __restrict__ Cout,
    int M, int N, int K, int c_f32) {
  __shared__ unsigned short As[128 * LDP];
  __shared__ unsigned short Bs[128 * LDP];
  int t = threadIdx.x;
  int lane = t & 63, wave = t >> 6;
  int m0 = blockIdx.y * 128, n0 = blockIdx.x * 128;
  int wm = (wave >> 1) * 64, wn = (wave & 1) * 64;
  int l15 = lane & 15, lk = lane >> 4;
  int lrow = t >> 2, lc8 = (t & 3) * 8;
  f32x4 acc[4][4] = {};

  for (int k0 = 0; k0 < K; k0 += 32) {
    *(bf16x8*)&As[lrow * LDP + lc8]        = *(const bf16x8*)&A[(size_t)(m0 + lrow) * K + k0 + lc8];
    *(bf16x8*)&As[(lrow + 64) * LDP + lc8] = *(const bf16x8*)&A[(size_t)(m0 + lrow + 64) * K + k0 + lc8];
    *(bf16x8*)&Bs[lrow * LDP + lc8]        = *(const bf16x8*)&Bt[(size_t)(n0 + lrow) * K + k0 + lc8];
    *(bf16x8*)&Bs[(lrow + 64) * LDP + lc8] = *(const bf16x8*)&Bt[(size_t)(n0 + lrow + 64) * K + k0 + lc8];
    __syncthreads();
    bf16x8 af[4], bfr[4];
#pragma unroll
    for (int mi = 0; mi < 4; mi++) af[mi]  = *(const bf16x8*)&As[(wm + mi * 16 + l15) * LDP + lk * 8];
#pragma unroll
    for (int ni = 0; ni < 4; ni++) bfr[ni] = *(const bf16x8*)&Bs[(wn + ni * 16 + l15) * LDP + lk * 8];
#pragma unroll
    for (int mi = 0; mi < 4; mi++)
#pragma unroll
      for (int ni = 0; ni < 4; ni++)
        acc[mi][ni] = __builtin_amdgcn_mfma_f32_16x16x32_bf16(af[mi], bfr[ni], acc[mi][ni], 0, 0, 0);
    __syncthreads();
  }
#pragma unroll
  for (int mi = 0; mi < 4; mi++)
#pragma unroll
    for (int ni = 0; ni < 4; ni++) {
      int col = n0 + wn + ni * 16 + l15;
      float bsv = bias ? bias[col] : 0.0f;
#pragma unroll
      for (int r = 0; r < 4; r++) {
        int row = m0 + wm + mi * 16 + lk * 4 + r;
        float val = acc[mi][ni][r] + bsv;
        if (c_f32) ((float*)Cout)[(size_t)row * N + col] = val;
        else ((unsigned short*)Cout)[(size_t)row * N + col] = f2bf(val);
      }
    }
}

// ---------------- stats: rsum[b,h,i] = sum_j exp(SCALE * dot(...)) ----------------
__global__ __launch_bounds__(256) void stats_kernel(
    const unsigned short* __restrict__ Q, const unsigned short* __restrict__ Kc,
    float* __restrict__ rsum, int NQ, int NK) {
  int b = blockIdx.z, h = blockIdx.y, i0 = blockIdx.x * 32;
  int t = threadIdx.x, lane = t & 63, wave = t >> 6;
  int l15 = lane & 15, lk = lane >> 4;
  const size_t qbase = ((size_t)b * NQ + i0) * INNER_ + h * DH_;
  bf16x8 af[2][2];
#pragma unroll
  for (int mi = 0; mi < 2; mi++)
#pragma unroll
    for (int ks = 0; ks < 2; ks++)
      af[mi][ks] = *(const bf16x8*)&Q[qbase + (size_t)(mi * 16 + l15) * INNER_ + ks * 32 + lk * 8];
  float racc[2][4] = {};
  for (int j0 = wave * 16; j0 < NK; j0 += 64) {
    const size_t kbase = ((size_t)b * NK + j0 + l15) * INNER_ + h * DH_ + lk * 8;
    bf16x8 b0 = *(const bf16x8*)&Kc[kbase];
    bf16x8 b1 = *(const bf16x8*)&Kc[kbase + 32];
#pragma unroll
    for (int mi = 0; mi < 2; mi++) {
      f32x4 acc = {};
      acc = __builtin_amdgcn_mfma_f32_16x16x32_bf16(af[mi][0], b0, acc, 0, 0, 0);
      acc = __builtin_amdgcn_mfma_f32_16x16x32_bf16(af[mi][1], b1, acc, 0, 0, 0);
#pragma unroll
      for (int r = 0; r < 4; r++) racc[mi][r] += __expf(acc[r] * SCALE_);
    }
  }
#pragma unroll
  for (int o = 1; o < 16; o <<= 1)
#pragma unroll
    for (int mi = 0; mi < 2; mi++)
#pragma unroll
      for (int r = 0; r < 4; r++) racc[mi][r] += __shfl_xor(racc[mi][r], o, 64);
  __shared__ float part[4][32];
  if (l15 == 0)
#pragma unroll
    for (int mi = 0; mi < 2; mi++)
#pragma unroll
      for (int r = 0; r < 4; r++) part[wave][mi * 16 + lk * 4 + r] = racc[mi][r];
  __syncthreads();
  if (t < 32)
    rsum[((size_t)b * H_ + h) * NQ + i0 + t] = part[0][t] + part[1][t] + part[2][t] + part[3][t];
}

// ---------------- fused attention: 32-i tile, 32-j iter, XCD-pinned ----------------
// v2: round-0 geometry (512 blocks, 4 waves, 2 blocks/CU) with phase-1 split by
// HEAD-GROUP instead of (isub,jstrip): wave w owns heads 4w..4w+3 for the full
// 32i x 32j tile. Per-wave Q = 4h x 2k x 2isub = 16 bf16x8 = 64 VGPR -> the
// WHOLE Q tile lives in registers, loaded once (no per-iter Q re-read). This
// removes 4 MB/XCD of Q streaming; per-XCD L2 set drops to the 2 MB K/V chunk
// -> L2-resident -> load latency ~250cy (was ~900 HBM-thrash), hidable by the
// 8 waves/CU. Phases 2/3 verbatim from round-0 (quarter = isub + 2*jstrip).
// 2 barriers/iter: P1 -> bar1 -> P2(mix) -> bar2 -> P3(PV) -> next P1 (K loads
// overlap PV; race-free: Pb readers finish before bar2, Ms writers after bar1).
#define MSROW 40
#define MSG   (32 * MSROW + 8)   // 1288 shorts per g; +8 breaks g-stride %32 banks
__global__ __launch_bounds__(256, 2) void fused_attn_kernel(
    const unsigned short* __restrict__ Q, const unsigned short* __restrict__ Kc,
    const unsigned short* __restrict__ Vt, const float* __restrict__ rsum,
    const float* __restrict__ thw,
    float* __restrict__ p0, float* __restrict__ p1,
    float* __restrict__ p2, float* __restrict__ p3,
    int NQ, int NK, int CHUNK) {
  __shared__ unsigned short Pb[4 * 256 * 16];   // 32 KB, quarter = isub + 2*jstrip
  __shared__ unsigned short Ms[16 * MSG];       // 41.2 KB
  __shared__ float rinvS[512];                  // [h][i 32]
  int n = blockIdx.x;
  int combo = n & 7;
  int b = combo >> 2, jc = combo & 3;
  int i0 = (n >> 3) * 32;
  float* __restrict__ Op = (jc == 0) ? p0 : (jc == 1) ? p1 : (jc == 2) ? p2 : p3;
  int t = threadIdx.x, lane = t & 63, wave = t >> 6;
  int l15 = lane & 15, lk = lane >> 4;

  rinvS[t]       = 1.0f / rsum[((size_t)b * H_ + (t >> 5)) * NQ + i0 + (t & 31)];
  rinvS[t + 256] = 1.0f / rsum[((size_t)b * H_ + ((t + 256) >> 5)) * NQ + i0 + (t & 31)];

  // thw B-frag: lane (l15=g, lk): k=lk*8+e; h=(lk&1)*8+e; lk<2 -> hi, else residual
  bf16x8 tfrag;
  {
    int part = lk >> 1, hb = (lk & 1) * 8;
#pragma unroll
    for (int e = 0; e < 8; e++) {
      float a = thw[l15 * H_ + hb + e];
      unsigned short hi = f2bf(a);
      tfrag[e] = (short)(part == 0 ? hi : f2bf(a - bf2f(hi)));
    }
  }
  __syncthreads();

  // ---- hoist the ENTIRE Q tile for this wave's 4 heads into registers ----
  // qpre[hh][isub][k]: Q row i0 + isub*16 + l15, head wave*4+hh, d-chunk k
  bf16x8 qpre[4][2][2];
#pragma unroll
  for (int hh = 0; hh < 4; hh++)
#pragma unroll
    for (int is = 0; is < 2; is++)
#pragma unroll
      for (int kk = 0; kk < 2; kk++)
        qpre[hh][is][kk] = *(const bf16x8*)&Q[((size_t)b * NQ + i0 + is * 16 + l15) * INNER_
                                              + (wave * 4 + hh) * 64 + kk * 32 + lk * 8];

  f32x4 acc[32] = {};  // [gi*8 + is*4 + nt]
  const int jbeg = jc * CHUNK;

  for (int js = 0; js < CHUNK; js += 32) {
    int j0 = jbeg + js;
    const unsigned short* Kb0 = Kc + ((size_t)b * NK + j0 + l15) * INNER_;
    const unsigned short* Kb1 = Kb0 + (size_t)16 * INNER_;
    // ---- phase 1: sim for 4 heads over full 32i x 32j; Q from regs ----
    unsigned int stage[2][2][4][2];  // [isub][jstrip][r][uint pair]
#pragma unroll
    for (int hh = 0; hh < 4; hh++) {
      int h = wave * 4 + hh;
      bf16x8 kb00 = *(const bf16x8*)&Kb0[h * 64 + lk * 8];
      bf16x8 kb01 = *(const bf16x8*)&Kb0[h * 64 + 32 + lk * 8];
      bf16x8 kb10 = *(const bf16x8*)&Kb1[h * 64 + lk * 8];
      bf16x8 kb11 = *(const bf16x8*)&Kb1[h * 64 + 32 + lk * 8];
#pragma unroll
      for (int is = 0; is < 2; is++) {
        f32x4 s0 = {}, s1 = {};
        s0 = __builtin_amdgcn_mfma_f32_16x16x32_bf16(qpre[hh][is][0], kb00, s0, 0, 0, 0);
        s0 = __builtin_amdgcn_mfma_f32_16x16x32_bf16(qpre[hh][is][1], kb01, s0, 0, 0, 0);
        s1 = __builtin_amdgcn_mfma_f32_16x16x32_bf16(qpre[hh][is][0], kb10, s1, 0, 0, 0);
        s1 = __builtin_amdgcn_mfma_f32_16x16x32_bf16(qpre[hh][is][1], kb11, s1, 0, 0, 0);
        f32x4 ri = *(const f32x4*)&rinvS[h * 32 + is * 16 + lk * 4];
#pragma unroll
        for (int r = 0; r < 4; r++) {
          unsigned int b0 = f2bf(__expf(s0[r] * SCALE_) * ri[r]);
          unsigned int b1 = f2bf(__expf(s1[r] * SCALE_) * ri[r]);
          if (hh & 1) { stage[is][0][r][hh >> 1] |= b0 << 16; stage[is][1][r][hh >> 1] |= b1 << 16; }
          else        { stage[is][0][r][hh >> 1]  = b0;       stage[is][1][r][hh >> 1]  = b1; }
        }
      }
    }
    // write P^T slices: quarter (isub,jstrip), rows pos = im*16+jl, h-cols wave*4..+3
#pragma unroll
    for (int is = 0; is < 2; is++)
#pragma unroll
      for (int jp = 0; jp < 2; jp++)
#pragma unroll
        for (int r = 0; r < 4; r++) {
          int row = (lk * 4 + r) * 16 + l15;          // pos = im*16 + jl
          int col = (wave * 4) ^ ((row & 1) << 3);    // xor-swizzle banks
          uint2 u = { stage[is][jp][r][0], stage[is][jp][r][1] };
          *(uint2*)&Pb[(is + jp * 2) * 256 * 16 + row * 16 + col] = u;
        }
    __syncthreads();   // bar1: all h-slices of Pb complete
    // ---- phase 2: MFMA mix; wave handles quarter (isub=w&1, jstrip=w>>1) ----
    {
      int isub = wave & 1, jstrip = wave >> 1;
      const unsigned short* pr = &Pb[(isub + jstrip * 2) * 256 * 16];
#pragma unroll
      for (int p = 0; p < 16; p++) {
        int row = p * 16 + l15;
        int col = ((lk & 1) << 3) ^ ((row & 1) << 3);
        bf16x8 af = *(const bf16x8*)&pr[row * 16 + col];
        f32x4 m = {};
        m = __builtin_amdgcn_mfma_f32_16x16x32_bf16(af, tfrag, m, 0, 0, 0);
        // D: col=l15 -> g; rows lk*4+r -> j = jstrip*16 + lk*4 + r; i = p
        ushort4 o;
        o.x = f2bf(m[0]); o.y = f2bf(m[1]); o.z = f2bf(m[2]); o.w = f2bf(m[3]);
        *(ushort4*)&Ms[l15 * MSG + (isub * 16 + p) * MSROW + jstrip * 16 + lk * 4] = o;
      }
    }
    __syncthreads();   // bar2: Ms complete
    // ---- phase 3: PV (wave owns g = wave*4..+3, both isubs) ----
#pragma unroll
    for (int gi = 0; gi < 4; gi++) {
      int g = wave * 4 + gi;
      bf16x8 ma0 = *(const bf16x8*)&Ms[g * MSG + l15 * MSROW + lk * 8];
      bf16x8 ma1 = *(const bf16x8*)&Ms[g * MSG + (16 + l15) * MSROW + lk * 8];
#pragma unroll
      for (int nt = 0; nt < 4; nt++) {
        const size_t vb = ((size_t)b * INNER_ + g * 64 + nt * 16 + l15) * NK + j0 + lk * 8;
        bf16x8 v0 = *(const bf16x8*)&Vt[vb];
        acc[gi * 8 + nt]     = __builtin_amdgcn_mfma_f32_16x16x32_bf16(ma0, v0, acc[gi * 8 + nt], 0, 0, 0);
        acc[gi * 8 + 4 + nt] = __builtin_amdgcn_mfma_f32_16x16x32_bf16(ma1, v0, acc[gi * 8 + 4 + nt], 0, 0, 0);
      }
    }
    // no barrier: next P1 writes Pb only (its readers finished before bar2);
    // next Ms writes are fenced by next bar1.
  }
#pragma unroll
  for (int gi = 0; gi < 4; gi++)
#pragma unroll
    for (int is = 0; is < 2; is++)
#pragma unroll
      for (int nt = 0; nt < 4; nt++) {
        int col = (wave * 4 + gi) * 64 + nt * 16 + l15;
#pragma unroll
        for (int r = 0; r < 4; r++)
          Op[((size_t)b * NQ + i0 + is * 16 + lk * 4 + r) * INNER_ + col] = acc[gi * 8 + is * 4 + nt][r];
      }
}

// ---------------- reduce 4 partials + cast to bf16 ----------------
__global__ __launch_bounds__(256) void reduce_cast_kernel(
    const float* __restrict__ p0, const float* __restrict__ p1,
    const float* __restrict__ p2, const float* __restrict__ p3,
    unsigned short* __restrict__ out, int n4) {
  int idx = blockIdx.x * 256 + threadIdx.x;
  if (idx >= n4) return;
  float4 v = ((const float4*)p0)[idx];
  float4 w = ((const float4*)p1)[idx];
  float4 a = ((const float4*)p2)[idx];
  float4 c = ((const float4*)p3)[idx];
  v.x += w.x + a.x + c.x; v.y += w.y + a.y + c.y;
  v.z += w.z + a.z + c.z; v.w += w.w + a.w + c.w;
  ushort4 o;
  o.x = f2bf(v.x); o.y = f2bf(v.y); o.z = f2bf(v.z); o.w = f2bf(v.w);
  ((ushort4*)out)[idx] = o;
}

// ---------------- launch ----------------
extern "C" void kernel_launch(void* const* d_in, const int* in_sizes, int n_in,
                              void* d_out, int out_size, void* d_ws, size_t ws_size,
                              hipStream_t stream) {
  const float* x      = (const float*)d_in[0];
  const float* ctx    = (const float*)d_in[1];
  const float* ln_g   = (const float*)d_in[2];
  const float* ln_b   = (const float*)d_in[3];
  const float* cln_g  = (const float*)d_in[4];
  const float* cln_b  = (const float*)d_in[5];
  const float* W_qk   = (const float*)d_in[6];
  const float* W_cqk  = (const float*)d_in[7];
  const float* W_v    = (const float*)d_in[8];
  const float* W_cv   = (const float*)d_in[9];
  const float* W_out  = (const float*)d_in[10];
  const float* b_out  = (const float*)d_in[11];
  const float* W_cout = (const float*)d_in[12];
  const float* b_cout = (const float*)d_in[13];
  const float* th_w   = (const float*)d_in[14];
  const float* cth_w  = (const float*)d_in[15];

  char* w = (char*)d_ws;
  const size_t SZ_ROW = (size_t)B_ * I_ * DIM_ * 2;   // 8.39 MB
  const size_t SZ_W   = (size_t)DIM_ * INNER_ * 2;    // 2.1 MB
  unsigned short* xn    = (unsigned short*)w; w += SZ_ROW;  // p0 overlay later
  unsigned short* cn    = (unsigned short*)w; w += SZ_ROW;
  unsigned short* Wqkt  = (unsigned short*)w; w += SZ_W;
  unsigned short* Wcqkt = (unsigned short*)w; w += SZ_W;
  unsigned short* Wvt   = (unsigned short*)w; w += SZ_W;
  unsigned short* Wcvt  = (unsigned short*)w; w += SZ_W;
  unsigned short* Woutt = (unsigned short*)w; w += SZ_W;
  unsigned short* Wcoutt= (unsigned short*)w; w += SZ_W;
  unsigned short* qk    = (unsigned short*)w; w += SZ_ROW;
  unsigned short* ck    = (unsigned short*)w; w += SZ_ROW;
  unsigned short* vv    = (unsigned short*)w; w += SZ_ROW;  // p1 overlay later
  unsigned short* cv    = (unsigned short*)w; w += SZ_ROW;
  unsigned short* vT    = (unsigned short*)w; w += SZ_ROW;
  unsigned short* cvT   = (unsigned short*)w; w += SZ_ROW;
  float* rsum = (float*)w; w += (size_t)B_ * H_ * I_ * 4;
  float* csum = (float*)w; w += (size_t)B_ * H_ * J_ * 4;
  unsigned short* Oh1 = (unsigned short*)w; w += SZ_ROW;
  unsigned short* Oh2 = (unsigned short*)w; w += SZ_ROW;

  // 4 partial buffers (16.78 MB each): p0 over xn+cn (dead after input GEMMs),
  // p1 over vv+cv (dead after transposes), p2/p3 fresh tail (fits: verified r2).
  const size_t PART = (size_t)B_ * I_ * INNER_ * 4;
  float* p0 = (float*)xn;
  float* p1 = (float*)vv;
  float* p2 = (float*)w;
  float* p3 = (float*)(w + PART);

  dim3 tb(32, 8);
  ln_cast_kernel<<<B_ * I_, 256, 0, stream>>>(x, ln_g, ln_b, xn);
  ln_cast_kernel<<<B_ * J_, 256, 0, stream>>>(ctx, cln_g, cln_b, cn);

  transpose_cast_f32<<<dim3(32, 32, 1), tb, 0, stream>>>(W_qk,   Wqkt,  DIM_, INNER_);
  transpose_cast_f32<<<dim3(32, 32, 1), tb, 0, stream>>>(W_cqk,  Wcqkt, DIM_, INNER_);
  transpose_cast_f32<<<dim3(32, 32, 1), tb, 0, stream>>>(W_v,    Wvt,   DIM_, INNER_);
  transpose_cast_f32<<<dim3(32, 32, 1), tb, 0, stream>>>(W_cv,   Wcvt,  DIM_, INNER_);
  transpose_cast_f32<<<dim3(32, 32, 1), tb, 0, stream>>>(W_out,  Woutt, INNER_, DIM_);
  transpose_cast_f32<<<dim3(32, 32, 1), tb, 0, stream>>>(W_cout, Wcoutt,INNER_, DIM_);

  gemm_bt<<<dim3(INNER_ / 128, (B_ * I_) / 128), 256, 0, stream>>>(xn, Wqkt,  nullptr, qk, B_ * I_, INNER_, DIM_, 0);
  gemm_bt<<<dim3(INNER_ / 128, (B_ * J_) / 128), 256, 0, stream>>>(cn, Wcqkt, nullptr, ck, B_ * J_, INNER_, DIM_, 0);
  gemm_bt<<<dim3(INNER_ / 128, (B_ * I_) / 128), 256, 0, stream>>>(xn, Wvt,   nullptr, vv, B_ * I_, INNER_, DIM_, 0);
  gemm_bt<<<dim3(INNER_ / 128, (B_ * J_) / 128), 256, 0, stream>>>(cn, Wcvt,  nullptr, cv, B_ * J_, INNER_, DIM_, 0);

  transpose_bf16<<<dim3(INNER_ / 32, I_ / 32, B_), tb, 0, stream>>>(vv, vT, I_, INNER_);
  transpose_bf16<<<dim3(INNER_ / 32, J_ / 32, B_), tb, 0, stream>>>(cv, cvT, J_, INNER_);

  stats_kernel<<<dim3(I_ / 32, H_, B_), 256, 0, stream>>>(qk, ck, rsum, I_, J_);
  stats_kernel<<<dim3(J_ / 32, H_, B_), 256, 0, stream>>>(ck, qk, csum, J_, I_);

  const int n4 = (B_ * I_ * INNER_) / 4;
  // dir1: softmax over j, rows i
  fused_attn_kernel<<<(I_ / 32) * 4 * B_, 256, 0, stream>>>(
      qk, ck, cvT, rsum, th_w, p0, p1, p2, p3, I_, J_, J_ / 4);
  reduce_cast_kernel<<<n4 / 256, 256, 0, stream>>>(p0, p1, p2, p3, Oh1, n4);
  // dir2: softmax over i, rows j
  fused_attn_kernel<<<(J_ / 32) * 4 * B_, 256, 0, stream>>>(
      ck, qk, vT, csum, cth_w, p0, p1, p2, p3, J_, I_, I_ / 4);
  reduce_cast_kernel<<<n4 / 256, 256, 0, stream>>>(p0, p1, p2, p3, Oh2, n4);

  gemm_bt<<<dim3(DIM_ / 128, (B_ * I_) / 128), 256, 0, stream>>>(Oh1, Woutt, b_out, (float*)d_out, B_ * I_, DIM_, INNER_, 1);
  gemm_bt<<<dim3(DIM_ / 128, (B_ * J_) / 128), 256, 0, stream>>>(Oh2, Wcoutt, b_cout, ((float*)d_out) + (size_t)B_ * I_ * DIM_, B_ * J_, DIM_, INNER_, 1);
}

// Round 3
// 806.370 us; speedup vs baseline: 1.9594x; 1.1467x over previous
//
#include <hip/hip_runtime.h>
#include <hip/hip_bf16.h>
#include <cstdint>

#define DIM_   1024
#define H_     16
#define DH_    64
#define INNER_ 1024
#define B_     2
#define I_     2048
#define J_     2048
#define SCALE_ 0.125f

using bf16x8 = __attribute__((ext_vector_type(8))) short;
using f32x4  = __attribute__((ext_vector_type(4))) float;

__device__ __forceinline__ unsigned short f2bf(float f) {
  unsigned int u = __float_as_uint(f);
  u = (u + 0x7FFFu + ((u >> 16) & 1u)) >> 16;
  return (unsigned short)u;
}
__device__ __forceinline__ float bf2f(unsigned short h) {
  return __uint_as_float(((unsigned int)h) << 16);
}

// ---------------- LayerNorm + cast to bf16 ----------------
__global__ __launch_bounds__(256) void ln_cast_kernel(
    const float* __restrict__ in, const float* __restrict__ g,
    const float* __restrict__ bb, unsigned short* __restrict__ out) {
  int row = blockIdx.x;
  int t = threadIdx.x;
  const float4* rp = (const float4*)(in + (size_t)row * DIM_);
  float4 v = rp[t];
  float s  = v.x + v.y + v.z + v.w;
  float ss = v.x * v.x + v.y * v.y + v.z * v.z + v.w * v.w;
  for (int o = 1; o < 64; o <<= 1) {
    s  += __shfl_xor(s, o, 64);
    ss += __shfl_xor(ss, o, 64);
  }
  __shared__ float ls[4], lss[4];
  int wave = t >> 6, lane = t & 63;
  if (lane == 0) { ls[wave] = s; lss[wave] = ss; }
  __syncthreads();
  s  = ls[0] + ls[1] + ls[2] + ls[3];
  ss = lss[0] + lss[1] + lss[2] + lss[3];
  float mu  = s * (1.0f / DIM_);
  float var = ss * (1.0f / DIM_) - mu * mu;
  float rstd = rsqrtf(var + 1e-5f);
  float4 gv = ((const float4*)g)[t];
  float4 bv = ((const float4*)bb)[t];
  ushort4 o4;
  o4.x = f2bf((v.x - mu) * rstd * gv.x + bv.x);
  o4.y = f2bf((v.y - mu) * rstd * gv.y + bv.y);
  o4.z = f2bf((v.z - mu) * rstd * gv.z + bv.z);
  o4.w = f2bf((v.w - mu) * rstd * gv.w + bv.w);
  ((ushort4*)(out + (size_t)row * DIM_))[t] = o4;
}

// ---------------- transpose + cast f32 -> bf16 ----------------
__global__ __launch_bounds__(256) void transpose_cast_f32(
    const float* __restrict__ in, unsigned short* __restrict__ out, int R, int C) {
  __shared__ float tile[32][33];
  int z = blockIdx.z;
  const float* ip = in + (size_t)z * R * C;
  unsigned short* op = out + (size_t)z * R * C;
  int c0 = blockIdx.x * 32, r0 = blockIdx.y * 32;
  int tx = threadIdx.x, ty = threadIdx.y;
  for (int k = 0; k < 4; k++)
    tile[ty * 4 + k][tx] = ip[(size_t)(r0 + ty * 4 + k) * C + c0 + tx];
  __syncthreads();
  for (int k = 0; k < 4; k++)
    op[(size_t)(c0 + ty * 4 + k) * R + r0 + tx] = f2bf(tile[tx][ty * 4 + k]);
}

// ---------------- transpose bf16 -> bf16 ----------------
__global__ __launch_bounds__(256) void transpose_bf16(
    const unsigned short* __restrict__ in, unsigned short* __restrict__ out, int R, int C) {
  __shared__ unsigned short tile[32][33];
  int z = blockIdx.z;
  const unsigned short* ip = in + (size_t)z * R * C;
  unsigned short* op = out + (size_t)z * R * C;
  int c0 = blockIdx.x * 32, r0 = blockIdx.y * 32;
  int tx = threadIdx.x, ty = threadIdx.y;
  for (int k = 0; k < 4; k++)
    tile[ty * 4 + k][tx] = ip[(size_t)(r0 + ty * 4 + k) * C + c0 + tx];
  __syncthreads();
  for (int k = 0; k < 4; k++)
    op[(size_t)(c0 + ty * 4 + k) * R + r0 + tx] = tile[tx][ty * 4 + k];
}

// ---------------- fused QKV GEMM: z in {x-side, ctx-side}, N=2048 ----------------
// Bt = [Wqk^T ; Wv^T] stacked (2048 rows x 1024 k). Output cols 0-1023 -> qk-buf,
// 1024-2047 -> v-buf (block-uniform split: 128-wide tiles never straddle 1024).
// Grid 16x32x2 = 1024 blocks = 4 blocks/CU (vs 1 for the old 4 separate GEMMs)
// -> staging latency hidden by co-resident blocks.
#define LDP 40
__global__ __launch_bounds__(256) void gemm_qkv(
    const unsigned short* __restrict__ A0, const unsigned short* __restrict__ A1,
    const unsigned short* __restrict__ Bt0, const unsigned short* __restrict__ Bt1,
    unsigned short* __restrict__ qkO0, unsigned short* __restrict__ vO0,
    unsigned short* __restrict__ qkO1, unsigned short* __restrict__ vO1,
    int M, int K) {
  __shared__ unsigned short As[128 * LDP];
  __shared__ unsigned short Bs[128 * LDP];
  int z = blockIdx.z;
  const unsigned short* A  = z ? A1 : A0;
  const unsigned short* Bt = z ? Bt1 : Bt0;
  unsigned short* qkO = z ? qkO1 : qkO0;
  unsigned short* vO  = z ? vO1 : vO0;
  int t = threadIdx.x;
  int lane = t & 63, wave = t >> 6;
  int m0 = blockIdx.y * 128, n0 = blockIdx.x * 128;
  int wm = (wave >> 1) * 64, wn = (wave & 1) * 64;
  int l15 = lane & 15, lk = lane >> 4;
  int lrow = t >> 2, lc8 = (t & 3) * 8;
  f32x4 acc[4][4] = {};

  for (int k0 = 0; k0 < K; k0 += 32) {
    *(bf16x8*)&As[lrow * LDP + lc8]        = *(const bf16x8*)&A[(size_t)(m0 + lrow) * K + k0 + lc8];
    *(bf16x8*)&As[(lrow + 64) * LDP + lc8] = *(const bf16x8*)&A[(size_t)(m0 + lrow + 64) * K + k0 + lc8];
    *(bf16x8*)&Bs[lrow * LDP + lc8]        = *(const bf16x8*)&Bt[(size_t)(n0 + lrow) * K + k0 + lc8];
    *(bf16x8*)&Bs[(lrow + 64) * LDP + lc8] = *(const bf16x8*)&Bt[(size_t)(n0 + lrow + 64) * K + k0 + lc8];
    __syncthreads();
    bf16x8 af[4], bfr[4];
#pragma unroll
    for (int mi = 0; mi < 4; mi++) af[mi]  = *(const bf16x8*)&As[(wm + mi * 16 + l15) * LDP + lk * 8];
#pragma unroll
    for (int ni = 0; ni < 4; ni++) bfr[ni] = *(const bf16x8*)&Bs[(wn + ni * 16 + l15) * LDP + lk * 8];
#pragma unroll
    for (int mi = 0; mi < 4; mi++)
#pragma unroll
      for (int ni = 0; ni < 4; ni++)
        acc[mi][ni] = __builtin_amdgcn_mfma_f32_16x16x32_bf16(af[mi], bfr[ni], acc[mi][ni], 0, 0, 0);
    __syncthreads();
  }
  unsigned short* dst = (n0 < 1024) ? qkO : vO;
  int nbase = n0 & 1023;
#pragma unroll
  for (int mi = 0; mi < 4; mi++)
#pragma unroll
    for (int ni = 0; ni < 4; ni++) {
      int col = nbase + wn + ni * 16 + l15;
#pragma unroll
      for (int r = 0; r < 4; r++) {
        int row = m0 + wm + mi * 16 + lk * 4 + r;
        dst[(size_t)row * INNER_ + col] = f2bf(acc[mi][ni][r]);
      }
    }
}

// ---------------- output GEMM: z in {dir1, dir2}, f32 + bias ----------------
__global__ __launch_bounds__(256) void gemm_out(
    const unsigned short* __restrict__ A0, const unsigned short* __restrict__ A1,
    const unsigned short* __restrict__ Bt0, const unsigned short* __restrict__ Bt1,
    const float* __restrict__ bias0, const float* __restrict__ bias1,
    float* __restrict__ C0, float* __restrict__ C1,
    int M, int N, int K) {
  __shared__ unsigned short As[128 * LDP];
  __shared__ unsigned short Bs[128 * LDP];
  int z = blockIdx.z;
  const unsigned short* A  = z ? A1 : A0;
  const unsigned short* Bt = z ? Bt1 : Bt0;
  const float* bias = z ? bias1 : bias0;
  float* Cout = z ? C1 : C0;
  int t = threadIdx.x;
  int lane = t & 63, wave = t >> 6;
  int m0 = blockIdx.y * 128, n0 = blockIdx.x * 128;
  int wm = (wave >> 1) * 64, wn = (wave & 1) * 64;
  int l15 = lane & 15, lk = lane >> 4;
  int lrow = t >> 2, lc8 = (t & 3) * 8;
  f32x4 acc[4][4] = {};

  for (int k0 = 0; k0 < K; k0 += 32) {
    *(bf16x8*)&As[lrow * LDP + lc8]        = *(const bf16x8*)&A[(size_t)(m0 + lrow) * K + k0 + lc8];
    *(bf16x8*)&As[(lrow + 64) * LDP + lc8] = *(const bf16x8*)&A[(size_t)(m0 + lrow + 64) * K + k0 + lc8];
    *(bf16x8*)&Bs[lrow * LDP + lc8]        = *(const bf16x8*)&Bt[(size_t)(n0 + lrow) * K + k0 + lc8];
    *(bf16x8*)&Bs[(lrow + 64) * LDP + lc8] = *(const bf16x8*)&Bt[(size_t)(n0 + lrow + 64) * K + k0 + lc8];
    __syncthreads();
    bf16x8 af[4], bfr[4];
#pragma unroll
    for (int mi = 0; mi < 4; mi++) af[mi]  = *(const bf16x8*)&As[(wm + mi * 16 + l15) * LDP + lk * 8];
#pragma unroll
    for (int ni = 0; ni < 4; ni++) bfr[ni] = *(const bf16x8*)&Bs[(wn + ni * 16 + l15) * LDP + lk * 8];
#pragma unroll
    for (int mi = 0; mi < 4; mi++)
#pragma unroll
      for (int ni = 0; ni < 4; ni++)
        acc[mi][ni] = __builtin_amdgcn_mfma_f32_16x16x32_bf16(af[mi], bfr[ni], acc[mi][ni], 0, 0, 0);
    __syncthreads();
  }
#pragma unroll
  for (int mi = 0; mi < 4; mi++)
#pragma unroll
    for (int ni = 0; ni < 4; ni++) {
      int col = n0 + wn + ni * 16 + l15;
      float bsv = bias[col];
#pragma unroll
      for (int r = 0; r < 4; r++) {
        int row = m0 + wm + mi * 16 + lk * 4 + r;
        Cout[(size_t)row * N + col] = acc[mi][ni][r] + bsv;
      }
    }
}

// ---------------- stats: both dirs + both b in one launch; 64-i tiles ----------------
// z = dir*2 + b. dir0: rsum over j for Q=qk; dir1: csum over i for Q=ck.
// 64-i tile halves per-block K re-read vs 32-i (256KB K slice covers 2x the rows).
__global__ __launch_bounds__(256) void stats_kernel(
    const unsigned short* __restrict__ qk, const unsigned short* __restrict__ ck,
    float* __restrict__ rsum, float* __restrict__ csum, int NQ, int NK) {
  int zz = blockIdx.z;
  int b = zz & 1, dir = zz >> 1;
  const unsigned short* Q  = dir ? ck : qk;
  const unsigned short* Kc = dir ? qk : ck;
  float* out = dir ? csum : rsum;
  int h = blockIdx.y, i0 = blockIdx.x * 64;
  int t = threadIdx.x, lane = t & 63, wave = t >> 6;
  int l15 = lane & 15, lk = lane >> 4;
  const size_t qbase = ((size_t)b * NQ + i0) * INNER_ + h * DH_;
  bf16x8 af[4][2];
#pragma unroll
  for (int mi = 0; mi < 4; mi++)
#pragma unroll
    for (int ks = 0; ks < 2; ks++)
      af[mi][ks] = *(const bf16x8*)&Q[qbase + (size_t)(mi * 16 + l15) * INNER_ + ks * 32 + lk * 8];
  float racc[4][4] = {};
  for (int j0 = wave * 16; j0 < NK; j0 += 64) {
    const size_t kbase = ((size_t)b * NK + j0 + l15) * INNER_ + h * DH_ + lk * 8;
    bf16x8 b0 = *(const bf16x8*)&Kc[kbase];
    bf16x8 b1 = *(const bf16x8*)&Kc[kbase + 32];
#pragma unroll
    for (int mi = 0; mi < 4; mi++) {
      f32x4 acc = {};
      acc = __builtin_amdgcn_mfma_f32_16x16x32_bf16(af[mi][0], b0, acc, 0, 0, 0);
      acc = __builtin_amdgcn_mfma_f32_16x16x32_bf16(af[mi][1], b1, acc, 0, 0, 0);
#pragma unroll
      for (int r = 0; r < 4; r++) racc[mi][r] += __expf(acc[r] * SCALE_);
    }
  }
#pragma unroll
  for (int o = 1; o < 16; o <<= 1)
#pragma unroll
    for (int mi = 0; mi < 4; mi++)
#pragma unroll
      for (int r = 0; r < 4; r++) racc[mi][r] += __shfl_xor(racc[mi][r], o, 64);
  __shared__ float part[4][64];
  if (l15 == 0)
#pragma unroll
    for (int mi = 0; mi < 4; mi++)
#pragma unroll
      for (int r = 0; r < 4; r++) part[wave][mi * 16 + lk * 4 + r] = racc[mi][r];
  __syncthreads();
  if (t < 64)
    out[((size_t)b * H_ + h) * NQ + i0 + t] = part[0][t] + part[1][t] + part[2][t] + part[3][t];
}

// ---------------- fused attention: 32-i tile, 32-j iter, XCD-pinned ----------------
// v2 structure (verified round 2) + s_setprio around MFMA clusters (T5):
// wave w owns heads 4w..4w+3; whole Q tile in registers; K/V chunk L2-resident
// per XCD. 2 barriers/iter; P3 overlaps next-iter K loads.
#define MSROW 40
#define MSG   (32 * MSROW + 8)   // 1288 shorts per g; +8 breaks g-stride %32 banks
__global__ __launch_bounds__(256, 2) void fused_attn_kernel(
    const unsigned short* __restrict__ Q, const unsigned short* __restrict__ Kc,
    const unsigned short* __restrict__ Vt, const float* __restrict__ rsum,
    const float* __restrict__ thw,
    float* __restrict__ p0, float* __restrict__ p1,
    float* __restrict__ p2, float* __restrict__ p3,
    int NQ, int NK, int CHUNK) {
  __shared__ unsigned short Pb[4 * 256 * 16];   // 32 KB, quarter = isub + 2*jstrip
  __shared__ unsigned short Ms[16 * MSG];       // 41.2 KB
  __shared__ float rinvS[512];                  // [h][i 32]
  int n = blockIdx.x;
  int combo = n & 7;
  int b = combo >> 2, jc = combo & 3;
  int i0 = (n >> 3) * 32;
  float* __restrict__ Op = (jc == 0) ? p0 : (jc == 1) ? p1 : (jc == 2) ? p2 : p3;
  int t = threadIdx.x, lane = t & 63, wave = t >> 6;
  int l15 = lane & 15, lk = lane >> 4;

  rinvS[t]       = 1.0f / rsum[((size_t)b * H_ + (t >> 5)) * NQ + i0 + (t & 31)];
  rinvS[t + 256] = 1.0f / rsum[((size_t)b * H_ + ((t + 256) >> 5)) * NQ + i0 + (t & 31)];

  // thw B-frag: lane (l15=g, lk): k=lk*8+e; h=(lk&1)*8+e; lk<2 -> hi, else residual
  bf16x8 tfrag;
  {
    int part = lk >> 1, hb = (lk & 1) * 8;
#pragma unroll
    for (int e = 0; e < 8; e++) {
      float a = thw[l15 * H_ + hb + e];
      unsigned short hi = f2bf(a);
      tfrag[e] = (short)(part == 0 ? hi : f2bf(a - bf2f(hi)));
    }
  }
  __syncthreads();

  // ---- hoist the ENTIRE Q tile for this wave's 4 heads into registers ----
  bf16x8 qpre[4][2][2];
#pragma unroll
  for (int hh = 0; hh < 4; hh++)
#pragma unroll
    for (int is = 0; is < 2; is++)
#pragma unroll
      for (int kk = 0; kk < 2; kk++)
        qpre[hh][is][kk] = *(const bf16x8*)&Q[((size_t)b * NQ + i0 + is * 16 + l15) * INNER_
                                              + (wave * 4 + hh) * 64 + kk * 32 + lk * 8];

  f32x4 acc[32] = {};  // [gi*8 + is*4 + nt]
  const int jbeg = jc * CHUNK;

  for (int js = 0; js < CHUNK; js += 32) {
    int j0 = jbeg + js;
    const unsigned short* Kb0 = Kc + ((size_t)b * NK + j0 + l15) * INNER_;
    const unsigned short* Kb1 = Kb0 + (size_t)16 * INNER_;
    // ---- phase 1: sim for 4 heads over full 32i x 32j; Q from regs ----
    unsigned int stage[2][2][4][2];  // [isub][jstrip][r][uint pair]
#pragma unroll
    for (int hh = 0; hh < 4; hh++) {
      int h = wave * 4 + hh;
      bf16x8 kb00 = *(const bf16x8*)&Kb0[h * 64 + lk * 8];
      bf16x8 kb01 = *(const bf16x8*)&Kb0[h * 64 + 32 + lk * 8];
      bf16x8 kb10 = *(const bf16x8*)&Kb1[h * 64 + lk * 8];
      bf16x8 kb11 = *(const bf16x8*)&Kb1[h * 64 + 32 + lk * 8];
#pragma unroll
      for (int is = 0; is < 2; is++) {
        f32x4 s0 = {}, s1 = {};
        __builtin_amdgcn_s_setprio(1);
        s0 = __builtin_amdgcn_mfma_f32_16x16x32_bf16(qpre[hh][is][0], kb00, s0, 0, 0, 0);
        s0 = __builtin_amdgcn_mfma_f32_16x16x32_bf16(qpre[hh][is][1], kb01, s0, 0, 0, 0);
        s1 = __builtin_amdgcn_mfma_f32_16x16x32_bf16(qpre[hh][is][0], kb10, s1, 0, 0, 0);
        s1 = __builtin_amdgcn_mfma_f32_16x16x32_bf16(qpre[hh][is][1], kb11, s1, 0, 0, 0);
        __builtin_amdgcn_s_setprio(0);
        f32x4 ri = *(const f32x4*)&rinvS[h * 32 + is * 16 + lk * 4];
#pragma unroll
        for (int r = 0; r < 4; r++) {
          unsigned int b0 = f2bf(__expf(s0[r] * SCALE_) * ri[r]);
          unsigned int b1 = f2bf(__expf(s1[r] * SCALE_) * ri[r]);
          if (hh & 1) { stage[is][0][r][hh >> 1] |= b0 << 16; stage[is][1][r][hh >> 1] |= b1 << 16; }
          else        { stage[is][0][r][hh >> 1]  = b0;       stage[is][1][r][hh >> 1]  = b1; }
        }
      }
    }
    // write P^T slices: quarter (isub,jstrip), rows pos = im*16+jl, h-cols wave*4..+3
#pragma unroll
    for (int is = 0; is < 2; is++)
#pragma unroll
      for (int jp = 0; jp < 2; jp++)
#pragma unroll
        for (int r = 0; r < 4; r++) {
          int row = (lk * 4 + r) * 16 + l15;          // pos = im*16 + jl
          int col = (wave * 4) ^ ((row & 1) << 3);    // xor-swizzle banks
          uint2 u = { stage[is][jp][r][0], stage[is][jp][r][1] };
          *(uint2*)&Pb[(is + jp * 2) * 256 * 16 + row * 16 + col] = u;
        }
    __syncthreads();   // bar1: all h-slices of Pb complete
    // ---- phase 2: MFMA mix; wave handles quarter (isub=w&1, jstrip=w>>1) ----
    {
      int isub = wave & 1, jstrip = wave >> 1;
      const unsigned short* pr = &Pb[(isub + jstrip * 2) * 256 * 16];
#pragma unroll
      for (int p = 0; p < 16; p++) {
        int row = p * 16 + l15;
        int col = ((lk & 1) << 3) ^ ((row & 1) << 3);
        bf16x8 af = *(const bf16x8*)&pr[row * 16 + col];
        f32x4 m = {};
        __builtin_amdgcn_s_setprio(1);
        m = __builtin_amdgcn_mfma_f32_16x16x32_bf16(af, tfrag, m, 0, 0, 0);
        __builtin_amdgcn_s_setprio(0);
        ushort4 o;
        o.x = f2bf(m[0]); o.y = f2bf(m[1]); o.z = f2bf(m[2]); o.w = f2bf(m[3]);
        *(ushort4*)&Ms[l15 * MSG + (isub * 16 + p) * MSROW + jstrip * 16 + lk * 4] = o;
      }
    }
    __syncthreads();   // bar2: Ms complete
    // ---- phase 3: PV (wave owns g = wave*4..+3, both isubs) ----
#pragma unroll
    for (int gi = 0; gi < 4; gi++) {
      int g = wave * 4 + gi;
      bf16x8 ma0 = *(const bf16x8*)&Ms[g * MSG + l15 * MSROW + lk * 8];
      bf16x8 ma1 = *(const bf16x8*)&Ms[g * MSG + (16 + l15) * MSROW + lk * 8];
#pragma unroll
      for (int nt = 0; nt < 4; nt++) {
        const size_t vb = ((size_t)b * INNER_ + g * 64 + nt * 16 + l15) * NK + j0 + lk * 8;
        bf16x8 v0 = *(const bf16x8*)&Vt[vb];
        __builtin_amdgcn_s_setprio(1);
        acc[gi * 8 + nt]     = __builtin_amdgcn_mfma_f32_16x16x32_bf16(ma0, v0, acc[gi * 8 + nt], 0, 0, 0);
        acc[gi * 8 + 4 + nt] = __builtin_amdgcn_mfma_f32_16x16x32_bf16(ma1, v0, acc[gi * 8 + 4 + nt], 0, 0, 0);
        __builtin_amdgcn_s_setprio(0);
      }
    }
    // no barrier: next P1 writes Pb only (its readers finished before bar2);
    // next Ms writes are fenced by next bar1.
  }
#pragma unroll
  for (int gi = 0; gi < 4; gi++)
#pragma unroll
    for (int is = 0; is < 2; is++)
#pragma unroll
      for (int nt = 0; nt < 4; nt++) {
        int col = (wave * 4 + gi) * 64 + nt * 16 + l15;
#pragma unroll
        for (int r = 0; r < 4; r++)
          Op[((size_t)b * NQ + i0 + is * 16 + lk * 4 + r) * INNER_ + col] = acc[gi * 8 + is * 4 + nt][r];
      }
}

// ---------------- reduce 4 partials + cast to bf16 ----------------
__global__ __launch_bounds__(256) void reduce_cast_kernel(
    const float* __restrict__ p0, const float* __restrict__ p1,
    const float* __restrict__ p2, const float* __restrict__ p3,
    unsigned short* __restrict__ out, int n4) {
  int idx = blockIdx.x * 256 + threadIdx.x;
  if (idx >= n4) return;
  float4 v = ((const float4*)p0)[idx];
  float4 w = ((const float4*)p1)[idx];
  float4 a = ((const float4*)p2)[idx];
  float4 c = ((const float4*)p3)[idx];
  v.x += w.x + a.x + c.x; v.y += w.y + a.y + c.y;
  v.z += w.z + a.z + c.z; v.w += w.w + a.w + c.w;
  ushort4 o;
  o.x = f2bf(v.x); o.y = f2bf(v.y); o.z = f2bf(v.z); o.w = f2bf(v.w);
  ((ushort4*)out)[idx] = o;
}

// ---------------- launch ----------------
extern "C" void kernel_launch(void* const* d_in, const int* in_sizes, int n_in,
                              void* d_out, int out_size, void* d_ws, size_t ws_size,
                              hipStream_t stream) {
  const float* x      = (const float*)d_in[0];
  const float* ctx    = (const float*)d_in[1];
  const float* ln_g   = (const float*)d_in[2];
  const float* ln_b   = (const float*)d_in[3];
  const float* cln_g  = (const float*)d_in[4];
  const float* cln_b  = (const float*)d_in[5];
  const float* W_qk   = (const float*)d_in[6];
  const float* W_cqk  = (const float*)d_in[7];
  const float* W_v    = (const float*)d_in[8];
  const float* W_cv   = (const float*)d_in[9];
  const float* W_out  = (const float*)d_in[10];
  const float* b_out  = (const float*)d_in[11];
  const float* W_cout = (const float*)d_in[12];
  const float* b_cout = (const float*)d_in[13];
  const float* th_w   = (const float*)d_in[14];
  const float* cth_w  = (const float*)d_in[15];

  char* w = (char*)d_ws;
  const size_t SZ_ROW = (size_t)B_ * I_ * DIM_ * 2;   // 8.39 MB
  const size_t SZ_W   = (size_t)DIM_ * INNER_ * 2;    // 2.1 MB
  unsigned short* xn    = (unsigned short*)w; w += SZ_ROW;  // p0 overlay later
  unsigned short* cn    = (unsigned short*)w; w += SZ_ROW;
  unsigned short* WqvX  = (unsigned short*)w; w += 2 * SZ_W;  // [Wqk^T ; Wv^T]
  unsigned short* WqvC  = (unsigned short*)w; w += 2 * SZ_W;  // [Wcqk^T ; Wcv^T]
  unsigned short* Woutt = (unsigned short*)w; w += SZ_W;
  unsigned short* Wcoutt= (unsigned short*)w; w += SZ_W;
  unsigned short* qk    = (unsigned short*)w; w += SZ_ROW;
  unsigned short* ck    = (unsigned short*)w; w += SZ_ROW;
  unsigned short* vv    = (unsigned short*)w; w += SZ_ROW;  // p1 overlay later
  unsigned short* cv    = (unsigned short*)w; w += SZ_ROW;
  unsigned short* vT    = (unsigned short*)w; w += SZ_ROW;
  unsigned short* cvT   = (unsigned short*)w; w += SZ_ROW;
  float* rsum = (float*)w; w += (size_t)B_ * H_ * I_ * 4;
  float* csum = (float*)w; w += (size_t)B_ * H_ * J_ * 4;
  unsigned short* Oh1 = (unsigned short*)w; w += SZ_ROW;
  unsigned short* Oh2 = (unsigned short*)w; w += SZ_ROW;

  // 4 partial buffers (16.78 MB each): p0 over xn+cn (dead after input GEMMs),
  // p1 over vv+cv (dead after transposes), p2/p3 fresh tail.
  const size_t PART = (size_t)B_ * I_ * INNER_ * 4;
  float* p0 = (float*)xn;
  float* p1 = (float*)vv;
  float* p2 = (float*)w;
  float* p3 = (float*)(w + PART);

  dim3 tb(32, 8);
  ln_cast_kernel<<<B_ * I_, 256, 0, stream>>>(x, ln_g, ln_b, xn);
  ln_cast_kernel<<<B_ * J_, 256, 0, stream>>>(ctx, cln_g, cln_b, cn);

  const size_t WOFF = (size_t)DIM_ * INNER_;  // elements
  transpose_cast_f32<<<dim3(32, 32, 1), tb, 0, stream>>>(W_qk,   WqvX,        DIM_, INNER_);
  transpose_cast_f32<<<dim3(32, 32, 1), tb, 0, stream>>>(W_v,    WqvX + WOFF, DIM_, INNER_);
  transpose_cast_f32<<<dim3(32, 32, 1), tb, 0, stream>>>(W_cqk,  WqvC,        DIM_, INNER_);
  transpose_cast_f32<<<dim3(32, 32, 1), tb, 0, stream>>>(W_cv,   WqvC + WOFF, DIM_, INNER_);
  transpose_cast_f32<<<dim3(32, 32, 1), tb, 0, stream>>>(W_out,  Woutt, INNER_, DIM_);
  transpose_cast_f32<<<dim3(32, 32, 1), tb, 0, stream>>>(W_cout, Wcoutt,INNER_, DIM_);

  // fused QKV: one launch, 4 products, 1024 blocks (4/CU)
  gemm_qkv<<<dim3(2 * INNER_ / 128, (B_ * I_) / 128, 2), 256, 0, stream>>>(
      xn, cn, WqvX, WqvC, qk, vv, ck, cv, B_ * I_, DIM_);

  transpose_bf16<<<dim3(INNER_ / 32, I_ / 32, B_), tb, 0, stream>>>(vv, vT, I_, INNER_);
  transpose_bf16<<<dim3(INNER_ / 32, J_ / 32, B_), tb, 0, stream>>>(cv, cvT, J_, INNER_);

  // stats: both dirs + both b, 64-i tiles, 2048 blocks
  stats_kernel<<<dim3(I_ / 64, H_, 4), 256, 0, stream>>>(qk, ck, rsum, csum, I_, J_);

  const int n4 = (B_ * I_ * INNER_) / 4;
  // dir1: softmax over j, rows i
  fused_attn_kernel<<<(I_ / 32) * 4 * B_, 256, 0, stream>>>(
      qk, ck, cvT, rsum, th_w, p0, p1, p2, p3, I_, J_, J_ / 4);
  reduce_cast_kernel<<<n4 / 256, 256, 0, stream>>>(p0, p1, p2, p3, Oh1, n4);
  // dir2: softmax over i, rows j
  fused_attn_kernel<<<(J_ / 32) * 4 * B_, 256, 0, stream>>>(
      ck, qk, vT, csum, cth_w, p0, p1, p2, p3, J_, I_, I_ / 4);
  reduce_cast_kernel<<<n4 / 256, 256, 0, stream>>>(p0, p1, p2, p3, Oh2, n4);

  // both output GEMMs in one launch (512 blocks, 2/CU)
  gemm_out<<<dim3(DIM_ / 128, (B_ * I_) / 128, 2), 256, 0, stream>>>(
      Oh1, Oh2, Woutt, Wcoutt, b_out, b_cout,
      (float*)d_out, ((float*)d_out) + (size_t)B_ * I_ * DIM_,
      B_ * I_, DIM_, INNER_);
}

// Round 4
// 775.824 us; speedup vs baseline: 2.0366x; 1.0394x over previous
//
#include <hip/hip_runtime.h>
#include <hip/hip_bf16.h>
#include <cstdint>

#define DIM_   1024
#define H_     16
#define DH_    64
#define INNER_ 1024
#define B_     2
#define I_     2048
#define J_     2048
#define SCALE_ 0.125f

using bf16x8 = __attribute__((ext_vector_type(8))) short;
using f32x4  = __attribute__((ext_vector_type(4))) float;

__device__ __forceinline__ unsigned short f2bf(float f) {
  unsigned int u = __float_as_uint(f);
  u = (u + 0x7FFFu + ((u >> 16) & 1u)) >> 16;
  return (unsigned short)u;
}
__device__ __forceinline__ float bf2f(unsigned short h) {
  return __uint_as_float(((unsigned int)h) << 16);
}

// async global->LDS, 16B per lane; LDS dest is wave-uniform base + lane*16
__device__ __forceinline__ void gld16(const unsigned short* g, unsigned short* l) {
  __builtin_amdgcn_global_load_lds(
      (const __attribute__((address_space(1))) unsigned int*)g,
      (__attribute__((address_space(3))) unsigned int*)l, 16, 0, 0);
}

// ---------------- LayerNorm + cast to bf16 ----------------
__global__ __launch_bounds__(256) void ln_cast_kernel(
    const float* __restrict__ in, const float* __restrict__ g,
    const float* __restrict__ bb, unsigned short* __restrict__ out) {
  int row = blockIdx.x;
  int t = threadIdx.x;
  const float4* rp = (const float4*)(in + (size_t)row * DIM_);
  float4 v = rp[t];
  float s  = v.x + v.y + v.z + v.w;
  float ss = v.x * v.x + v.y * v.y + v.z * v.z + v.w * v.w;
  for (int o = 1; o < 64; o <<= 1) {
    s  += __shfl_xor(s, o, 64);
    ss += __shfl_xor(ss, o, 64);
  }
  __shared__ float ls[4], lss[4];
  int wave = t >> 6, lane = t & 63;
  if (lane == 0) { ls[wave] = s; lss[wave] = ss; }
  __syncthreads();
  s  = ls[0] + ls[1] + ls[2] + ls[3];
  ss = lss[0] + lss[1] + lss[2] + lss[3];
  float mu  = s * (1.0f / DIM_);
  float var = ss * (1.0f / DIM_) - mu * mu;
  float rstd = rsqrtf(var + 1e-5f);
  float4 gv = ((const float4*)g)[t];
  float4 bv = ((const float4*)bb)[t];
  ushort4 o4;
  o4.x = f2bf((v.x - mu) * rstd * gv.x + bv.x);
  o4.y = f2bf((v.y - mu) * rstd * gv.y + bv.y);
  o4.z = f2bf((v.z - mu) * rstd * gv.z + bv.z);
  o4.w = f2bf((v.w - mu) * rstd * gv.w + bv.w);
  ((ushort4*)(out + (size_t)row * DIM_))[t] = o4;
}

// ---------------- transpose + cast f32 -> bf16 ----------------
__global__ __launch_bounds__(256) void transpose_cast_f32(
    const float* __restrict__ in, unsigned short* __restrict__ out, int R, int C) {
  __shared__ float tile[32][33];
  int z = blockIdx.z;
  const float* ip = in + (size_t)z * R * C;
  unsigned short* op = out + (size_t)z * R * C;
  int c0 = blockIdx.x * 32, r0 = blockIdx.y * 32;
  int tx = threadIdx.x, ty = threadIdx.y;
  for (int k = 0; k < 4; k++)
    tile[ty * 4 + k][tx] = ip[(size_t)(r0 + ty * 4 + k) * C + c0 + tx];
  __syncthreads();
  for (int k = 0; k < 4; k++)
    op[(size_t)(c0 + ty * 4 + k) * R + r0 + tx] = f2bf(tile[tx][ty * 4 + k]);
}

// ---------------- transpose bf16 -> bf16 ----------------
__global__ __launch_bounds__(256) void transpose_bf16(
    const unsigned short* __restrict__ in, unsigned short* __restrict__ out, int R, int C) {
  __shared__ unsigned short tile[32][33];
  int z = blockIdx.z;
  const unsigned short* ip = in + (size_t)z * R * C;
  unsigned short* op = out + (size_t)z * R * C;
  int c0 = blockIdx.x * 32, r0 = blockIdx.y * 32;
  int tx = threadIdx.x, ty = threadIdx.y;
  for (int k = 0; k < 4; k++)
    tile[ty * 4 + k][tx] = ip[(size_t)(r0 + ty * 4 + k) * C + c0 + tx];
  __syncthreads();
  for (int k = 0; k < 4; k++)
    op[(size_t)(c0 + ty * 4 + k) * R + r0 + tx] = tile[tx][ty * 4 + k];
}

// ---------------- fused QKV GEMM: m97-style global_load_lds staging ----------------
// Linear LDS [128][32] (no padding: gload_lds writes wave-uniform base + lane*16).
// Per k-step: 4 gload_lds_dwordx4 (A:2, B:2) -> barrier -> ds_read_b128 frags ->
// 16 MFMA -> barrier. Output cols 0-1023 -> qk-buf, 1024-2047 -> v-buf.
__global__ __launch_bounds__(256) void gemm_qkv(
    const unsigned short* __restrict__ A0, const unsigned short* __restrict__ A1,
    const unsigned short* __restrict__ Bt0, const unsigned short* __restrict__ Bt1,
    unsigned short* __restrict__ qkO0, unsigned short* __restrict__ vO0,
    unsigned short* __restrict__ qkO1, unsigned short* __restrict__ vO1,
    int M, int K) {
  __shared__ unsigned short As[128 * 32];
  __shared__ unsigned short Bs[128 * 32];
  int z = blockIdx.z;
  const unsigned short* A  = z ? A1 : A0;
  const unsigned short* Bt = z ? Bt1 : Bt0;
  unsigned short* qkO = z ? qkO1 : qkO0;
  unsigned short* vO  = z ? vO1 : vO0;
  int t = threadIdx.x;
  int lane = t & 63, wave = t >> 6;
  int m0 = blockIdx.y * 128, n0 = blockIdx.x * 128;
  int wm = (wave >> 1) * 64, wn = (wave & 1) * 64;
  int l15 = lane & 15, lk = lane >> 4;
  int srow = t >> 2, scol = (t & 3) * 8;   // staging: row t/4, elem col (t&3)*8
  f32x4 acc[4][4] = {};

  for (int k0 = 0; k0 < K; k0 += 32) {
    gld16(&A[(size_t)(m0 + srow) * K + k0 + scol],       &As[wave * 512]);
    gld16(&A[(size_t)(m0 + srow + 64) * K + k0 + scol],  &As[2048 + wave * 512]);
    gld16(&Bt[(size_t)(n0 + srow) * K + k0 + scol],      &Bs[wave * 512]);
    gld16(&Bt[(size_t)(n0 + srow + 64) * K + k0 + scol], &Bs[2048 + wave * 512]);
    __syncthreads();
    bf16x8 af[4], bfr[4];
#pragma unroll
    for (int mi = 0; mi < 4; mi++) af[mi]  = *(const bf16x8*)&As[(wm + mi * 16 + l15) * 32 + lk * 8];
#pragma unroll
    for (int ni = 0; ni < 4; ni++) bfr[ni] = *(const bf16x8*)&Bs[(wn + ni * 16 + l15) * 32 + lk * 8];
#pragma unroll
    for (int mi = 0; mi < 4; mi++)
#pragma unroll
      for (int ni = 0; ni < 4; ni++)
        acc[mi][ni] = __builtin_amdgcn_mfma_f32_16x16x32_bf16(af[mi], bfr[ni], acc[mi][ni], 0, 0, 0);
    __syncthreads();
  }
  unsigned short* dst = (n0 < 1024) ? qkO : vO;
  int nbase = n0 & 1023;
#pragma unroll
  for (int mi = 0; mi < 4; mi++)
#pragma unroll
    for (int ni = 0; ni < 4; ni++) {
      int col = nbase + wn + ni * 16 + l15;
#pragma unroll
      for (int r = 0; r < 4; r++) {
        int row = m0 + wm + mi * 16 + lk * 4 + r;
        dst[(size_t)row * INNER_ + col] = f2bf(acc[mi][ni][r]);
      }
    }
}

// ---------------- output GEMM: z in {dir1, dir2}, f32 + bias; gload_lds staging ----
__global__ __launch_bounds__(256) void gemm_out(
    const unsigned short* __restrict__ A0, const unsigned short* __restrict__ A1,
    const unsigned short* __restrict__ Bt0, const unsigned short* __restrict__ Bt1,
    const float* __restrict__ bias0, const float* __restrict__ bias1,
    float* __restrict__ C0, float* __restrict__ C1,
    int M, int N, int K) {
  __shared__ unsigned short As[128 * 32];
  __shared__ unsigned short Bs[128 * 32];
  int z = blockIdx.z;
  const unsigned short* A  = z ? A1 : A0;
  const unsigned short* Bt = z ? Bt1 : Bt0;
  const float* bias = z ? bias1 : bias0;
  float* Cout = z ? C1 : C0;
  int t = threadIdx.x;
  int lane = t & 63, wave = t >> 6;
  int m0 = blockIdx.y * 128, n0 = blockIdx.x * 128;
  int wm = (wave >> 1) * 64, wn = (wave & 1) * 64;
  int l15 = lane & 15, lk = lane >> 4;
  int srow = t >> 2, scol = (t & 3) * 8;
  f32x4 acc[4][4] = {};

  for (int k0 = 0; k0 < K; k0 += 32) {
    gld16(&A[(size_t)(m0 + srow) * K + k0 + scol],       &As[wave * 512]);
    gld16(&A[(size_t)(m0 + srow + 64) * K + k0 + scol],  &As[2048 + wave * 512]);
    gld16(&Bt[(size_t)(n0 + srow) * K + k0 + scol],      &Bs[wave * 512]);
    gld16(&Bt[(size_t)(n0 + srow + 64) * K + k0 + scol], &Bs[2048 + wave * 512]);
    __syncthreads();
    bf16x8 af[4], bfr[4];
#pragma unroll
    for (int mi = 0; mi < 4; mi++) af[mi]  = *(const bf16x8*)&As[(wm + mi * 16 + l15) * 32 + lk * 8];
#pragma unroll
    for (int ni = 0; ni < 4; ni++) bfr[ni] = *(const bf16x8*)&Bs[(wn + ni * 16 + l15) * 32 + lk * 8];
#pragma unroll
    for (int mi = 0; mi < 4; mi++)
#pragma unroll
      for (int ni = 0; ni < 4; ni++)
        acc[mi][ni] = __builtin_amdgcn_mfma_f32_16x16x32_bf16(af[mi], bfr[ni], acc[mi][ni], 0, 0, 0);
    __syncthreads();
  }
#pragma unroll
  for (int mi = 0; mi < 4; mi++)
#pragma unroll
    for (int ni = 0; ni < 4; ni++) {
      int col = n0 + wn + ni * 16 + l15;
      float bsv = bias[col];
#pragma unroll
      for (int r = 0; r < 4; r++) {
        int row = m0 + wm + mi * 16 + lk * 4 + r;
        Cout[(size_t)row * N + col] = acc[mi][ni][r] + bsv;
      }
    }
}

// ---------------- stats: both dirs + both b in one launch; 64-i tiles ----------------
__global__ __launch_bounds__(256) void stats_kernel(
    const unsigned short* __restrict__ qk, const unsigned short* __restrict__ ck,
    float* __restrict__ rsum, float* __restrict__ csum, int NQ, int NK) {
  int zz = blockIdx.z;
  int b = zz & 1, dir = zz >> 1;
  const unsigned short* Q  = dir ? ck : qk;
  const unsigned short* Kc = dir ? qk : ck;
  float* out = dir ? csum : rsum;
  int h = blockIdx.y, i0 = blockIdx.x * 64;
  int t = threadIdx.x, lane = t & 63, wave = t >> 6;
  int l15 = lane & 15, lk = lane >> 4;
  const size_t qbase = ((size_t)b * NQ + i0) * INNER_ + h * DH_;
  bf16x8 af[4][2];
#pragma unroll
  for (int mi = 0; mi < 4; mi++)
#pragma unroll
    for (int ks = 0; ks < 2; ks++)
      af[mi][ks] = *(const bf16x8*)&Q[qbase + (size_t)(mi * 16 + l15) * INNER_ + ks * 32 + lk * 8];
  float racc[4][4] = {};
  for (int j0 = wave * 16; j0 < NK; j0 += 64) {
    const size_t kbase = ((size_t)b * NK + j0 + l15) * INNER_ + h * DH_ + lk * 8;
    bf16x8 b0 = *(const bf16x8*)&Kc[kbase];
    bf16x8 b1 = *(const bf16x8*)&Kc[kbase + 32];
#pragma unroll
    for (int mi = 0; mi < 4; mi++) {
      f32x4 acc = {};
      acc = __builtin_amdgcn_mfma_f32_16x16x32_bf16(af[mi][0], b0, acc, 0, 0, 0);
      acc = __builtin_amdgcn_mfma_f32_16x16x32_bf16(af[mi][1], b1, acc, 0, 0, 0);
#pragma unroll
      for (int r = 0; r < 4; r++) racc[mi][r] += __expf(acc[r] * SCALE_);
    }
  }
#pragma unroll
  for (int o = 1; o < 16; o <<= 1)
#pragma unroll
    for (int mi = 0; mi < 4; mi++)
#pragma unroll
      for (int r = 0; r < 4; r++) racc[mi][r] += __shfl_xor(racc[mi][r], o, 64);
  __shared__ float part[4][64];
  if (l15 == 0)
#pragma unroll
    for (int mi = 0; mi < 4; mi++)
#pragma unroll
      for (int r = 0; r < 4; r++) part[wave][mi * 16 + lk * 4 + r] = racc[mi][r];
  __syncthreads();
  if (t < 64)
    out[((size_t)b * H_ + h) * NQ + i0 + t] = part[0][t] + part[1][t] + part[2][t] + part[3][t];
}

// ---------------- fused attention: 32-i tile, 32-j iter, XCD-pinned ----------------
// Round-2 verified structure (no setprio — measured −7µs/dispatch to remove):
// wave w owns heads 4w..4w+3; whole Q tile in registers; K/V chunk L2-resident
// per XCD. 2 barriers/iter; P3 overlaps next-iter K loads.
#define MSROW 40
#define MSG   (32 * MSROW + 8)   // 1288 shorts per g; +8 breaks g-stride %32 banks
__global__ __launch_bounds__(256, 2) void fused_attn_kernel(
    const unsigned short* __restrict__ Q, const unsigned short* __restrict__ Kc,
    const unsigned short* __restrict__ Vt, const float* __restrict__ rsum,
    const float* __restrict__ thw,
    float* __restrict__ p0, float* __restrict__ p1,
    float* __restrict__ p2, float* __restrict__ p3,
    int NQ, int NK, int CHUNK) {
  __shared__ unsigned short Pb[4 * 256 * 16];   // 32 KB, quarter = isub + 2*jstrip
  __shared__ unsigned short Ms[16 * MSG];       // 41.2 KB
  __shared__ float rinvS[512];                  // [h][i 32]
  int n = blockIdx.x;
  int combo = n & 7;
  int b = combo >> 2, jc = combo & 3;
  int i0 = (n >> 3) * 32;
  float* __restrict__ Op = (jc == 0) ? p0 : (jc == 1) ? p1 : (jc == 2) ? p2 : p3;
  int t = threadIdx.x, lane = t & 63, wave = t >> 6;
  int l15 = lane & 15, lk = lane >> 4;

  rinvS[t]       = 1.0f / rsum[((size_t)b * H_ + (t >> 5)) * NQ + i0 + (t & 31)];
  rinvS[t + 256] = 1.0f / rsum[((size_t)b * H_ + ((t + 256) >> 5)) * NQ + i0 + (t & 31)];

  // thw B-frag: lane (l15=g, lk): k=lk*8+e; h=(lk&1)*8+e; lk<2 -> hi, else residual
  bf16x8 tfrag;
  {
    int part = lk >> 1, hb = (lk & 1) * 8;
#pragma unroll
    for (int e = 0; e < 8; e++) {
      float a = thw[l15 * H_ + hb + e];
      unsigned short hi = f2bf(a);
      tfrag[e] = (short)(part == 0 ? hi : f2bf(a - bf2f(hi)));
    }
  }
  __syncthreads();

  // ---- hoist the ENTIRE Q tile for this wave's 4 heads into registers ----
  bf16x8 qpre[4][2][2];
#pragma unroll
  for (int hh = 0; hh < 4; hh++)
#pragma unroll
    for (int is = 0; is < 2; is++)
#pragma unroll
      for (int kk = 0; kk < 2; kk++)
        qpre[hh][is][kk] = *(const bf16x8*)&Q[((size_t)b * NQ + i0 + is * 16 + l15) * INNER_
                                              + (wave * 4 + hh) * 64 + kk * 32 + lk * 8];

  f32x4 acc[32] = {};  // [gi*8 + is*4 + nt]
  const int jbeg = jc * CHUNK;

  for (int js = 0; js < CHUNK; js += 32) {
    int j0 = jbeg + js;
    const unsigned short* Kb0 = Kc + ((size_t)b * NK + j0 + l15) * INNER_;
    const unsigned short* Kb1 = Kb0 + (size_t)16 * INNER_;
    // ---- phase 1: sim for 4 heads over full 32i x 32j; Q from regs ----
    unsigned int stage[2][2][4][2];  // [isub][jstrip][r][uint pair]
#pragma unroll
    for (int hh = 0; hh < 4; hh++) {
      int h = wave * 4 + hh;
      bf16x8 kb00 = *(const bf16x8*)&Kb0[h * 64 + lk * 8];
      bf16x8 kb01 = *(const bf16x8*)&Kb0[h * 64 + 32 + lk * 8];
      bf16x8 kb10 = *(const bf16x8*)&Kb1[h * 64 + lk * 8];
      bf16x8 kb11 = *(const bf16x8*)&Kb1[h * 64 + 32 + lk * 8];
#pragma unroll
      for (int is = 0; is < 2; is++) {
        f32x4 s0 = {}, s1 = {};
        s0 = __builtin_amdgcn_mfma_f32_16x16x32_bf16(qpre[hh][is][0], kb00, s0, 0, 0, 0);
        s0 = __builtin_amdgcn_mfma_f32_16x16x32_bf16(qpre[hh][is][1], kb01, s0, 0, 0, 0);
        s1 = __builtin_amdgcn_mfma_f32_16x16x32_bf16(qpre[hh][is][0], kb10, s1, 0, 0, 0);
        s1 = __builtin_amdgcn_mfma_f32_16x16x32_bf16(qpre[hh][is][1], kb11, s1, 0, 0, 0);
        f32x4 ri = *(const f32x4*)&rinvS[h * 32 + is * 16 + lk * 4];
#pragma unroll
        for (int r = 0; r < 4; r++) {
          unsigned int b0 = f2bf(__expf(s0[r] * SCALE_) * ri[r]);
          unsigned int b1 = f2bf(__expf(s1[r] * SCALE_) * ri[r]);
          if (hh & 1) { stage[is][0][r][hh >> 1] |= b0 << 16; stage[is][1][r][hh >> 1] |= b1 << 16; }
          else        { stage[is][0][r][hh >> 1]  = b0;       stage[is][1][r][hh >> 1]  = b1; }
        }
      }
    }
    // write P^T slices: quarter (isub,jstrip), rows pos = im*16+jl, h-cols wave*4..+3
#pragma unroll
    for (int is = 0; is < 2; is++)
#pragma unroll
      for (int jp = 0; jp < 2; jp++)
#pragma unroll
        for (int r = 0; r < 4; r++) {
          int row = (lk * 4 + r) * 16 + l15;          // pos = im*16 + jl
          int col = (wave * 4) ^ ((row & 1) << 3);    // xor-swizzle banks
          uint2 u = { stage[is][jp][r][0], stage[is][jp][r][1] };
          *(uint2*)&Pb[(is + jp * 2) * 256 * 16 + row * 16 + col] = u;
        }
    __syncthreads();   // bar1: all h-slices of Pb complete
    // ---- phase 2: MFMA mix; wave handles quarter (isub=w&1, jstrip=w>>1) ----
    {
      int isub = wave & 1, jstrip = wave >> 1;
      const unsigned short* pr = &Pb[(isub + jstrip * 2) * 256 * 16];
#pragma unroll
      for (int p = 0; p < 16; p++) {
        int row = p * 16 + l15;
        int col = ((lk & 1) << 3) ^ ((row & 1) << 3);
        bf16x8 af = *(const bf16x8*)&pr[row * 16 + col];
        f32x4 m = {};
        m = __builtin_amdgcn_mfma_f32_16x16x32_bf16(af, tfrag, m, 0, 0, 0);
        ushort4 o;
        o.x = f2bf(m[0]); o.y = f2bf(m[1]); o.z = f2bf(m[2]); o.w = f2bf(m[3]);
        *(ushort4*)&Ms[l15 * MSG + (isub * 16 + p) * MSROW + jstrip * 16 + lk * 4] = o;
      }
    }
    __syncthreads();   // bar2: Ms complete
    // ---- phase 3: PV (wave owns g = wave*4..+3, both isubs) ----
#pragma unroll
    for (int gi = 0; gi < 4; gi++) {
      int g = wave * 4 + gi;
      bf16x8 ma0 = *(const bf16x8*)&Ms[g * MSG + l15 * MSROW + lk * 8];
      bf16x8 ma1 = *(const bf16x8*)&Ms[g * MSG + (16 + l15) * MSROW + lk * 8];
#pragma unroll
      for (int nt = 0; nt < 4; nt++) {
        const size_t vb = ((size_t)b * INNER_ + g * 64 + nt * 16 + l15) * NK + j0 + lk * 8;
        bf16x8 v0 = *(const bf16x8*)&Vt[vb];
        acc[gi * 8 + nt]     = __builtin_amdgcn_mfma_f32_16x16x32_bf16(ma0, v0, acc[gi * 8 + nt], 0, 0, 0);
        acc[gi * 8 + 4 + nt] = __builtin_amdgcn_mfma_f32_16x16x32_bf16(ma1, v0, acc[gi * 8 + 4 + nt], 0, 0, 0);
      }
    }
    // no barrier: next P1 writes Pb only (its readers finished before bar2);
    // next Ms writes are fenced by next bar1.
  }
#pragma unroll
  for (int gi = 0; gi < 4; gi++)
#pragma unroll
    for (int is = 0; is < 2; is++)
#pragma unroll
      for (int nt = 0; nt < 4; nt++) {
        int col = (wave * 4 + gi) * 64 + nt * 16 + l15;
#pragma unroll
        for (int r = 0; r < 4; r++)
          Op[((size_t)b * NQ + i0 + is * 16 + lk * 4 + r) * INNER_ + col] = acc[gi * 8 + is * 4 + nt][r];
      }
}

// ---------------- reduce 4 partials + cast to bf16 ----------------
__global__ __launch_bounds__(256) void reduce_cast_kernel(
    const float* __restrict__ p0, const float* __restrict__ p1,
    const float* __restrict__ p2, const float* __restrict__ p3,
    unsigned short* __restrict__ out, int n4) {
  int idx = blockIdx.x * 256 + threadIdx.x;
  if (idx >= n4) return;
  float4 v = ((const float4*)p0)[idx];
  float4 w = ((const float4*)p1)[idx];
  float4 a = ((const float4*)p2)[idx];
  float4 c = ((const float4*)p3)[idx];
  v.x += w.x + a.x + c.x; v.y += w.y + a.y + c.y;
  v.z += w.z + a.z + c.z; v.w += w.w + a.w + c.w;
  ushort4 o;
  o.x = f2bf(v.x); o.y = f2bf(v.y); o.z = f2bf(v.z); o.w = f2bf(v.w);
  ((ushort4*)out)[idx] = o;
}

// ---------------- launch ----------------
extern "C" void kernel_launch(void* const* d_in, const int* in_sizes, int n_in,
                              void* d_out, int out_size, void* d_ws, size_t ws_size,
                              hipStream_t stream) {
  const float* x      = (const float*)d_in[0];
  const float* ctx    = (const float*)d_in[1];
  const float* ln_g   = (const float*)d_in[2];
  const float* ln_b   = (const float*)d_in[3];
  const float* cln_g  = (const float*)d_in[4];
  const float* cln_b  = (const float*)d_in[5];
  const float* W_qk   = (const float*)d_in[6];
  const float* W_cqk  = (const float*)d_in[7];
  const float* W_v    = (const float*)d_in[8];
  const float* W_cv   = (const float*)d_in[9];
  const float* W_out  = (const float*)d_in[10];
  const float* b_out  = (const float*)d_in[11];
  const float* W_cout = (const float*)d_in[12];
  const float* b_cout = (const float*)d_in[13];
  const float* th_w   = (const float*)d_in[14];
  const float* cth_w  = (const float*)d_in[15];

  char* w = (char*)d_ws;
  const size_t SZ_ROW = (size_t)B_ * I_ * DIM_ * 2;   // 8.39 MB
  const size_t SZ_W   = (size_t)DIM_ * INNER_ * 2;    // 2.1 MB
  unsigned short* xn    = (unsigned short*)w; w += SZ_ROW;  // p0 overlay later
  unsigned short* cn    = (unsigned short*)w; w += SZ_ROW;
  unsigned short* WqvX  = (unsigned short*)w; w += 2 * SZ_W;  // [Wqk^T ; Wv^T]
  unsigned short* WqvC  = (unsigned short*)w; w += 2 * SZ_W;  // [Wcqk^T ; Wcv^T]
  unsigned short* Woutt = (unsigned short*)w; w += SZ_W;
  unsigned short* Wcoutt= (unsigned short*)w; w += SZ_W;
  unsigned short* qk    = (unsigned short*)w; w += SZ_ROW;
  unsigned short* ck    = (unsigned short*)w; w += SZ_ROW;
  unsigned short* vv    = (unsigned short*)w; w += SZ_ROW;  // p1 overlay later
  unsigned short* cv    = (unsigned short*)w; w += SZ_ROW;
  unsigned short* vT    = (unsigned short*)w; w += SZ_ROW;
  unsigned short* cvT   = (unsigned short*)w; w += SZ_ROW;
  float* rsum = (float*)w; w += (size_t)B_ * H_ * I_ * 4;
  float* csum = (float*)w; w += (size_t)B_ * H_ * J_ * 4;
  unsigned short* Oh1 = (unsigned short*)w; w += SZ_ROW;
  unsigned short* Oh2 = (unsigned short*)w; w += SZ_ROW;

  // 4 partial buffers (16.78 MB each): p0 over xn+cn (dead after input GEMMs),
  // p1 over vv+cv (dead after transposes), p2/p3 fresh tail.
  const size_t PART = (size_t)B_ * I_ * INNER_ * 4;
  float* p0 = (float*)xn;
  float* p1 = (float*)vv;
  float* p2 = (float*)w;
  float* p3 = (float*)(w + PART);

  dim3 tb(32, 8);
  ln_cast_kernel<<<B_ * I_, 256, 0, stream>>>(x, ln_g, ln_b, xn);
  ln_cast_kernel<<<B_ * J_, 256, 0, stream>>>(ctx, cln_g, cln_b, cn);

  const size_t WOFF = (size_t)DIM_ * INNER_;  // elements
  transpose_cast_f32<<<dim3(32, 32, 1), tb, 0, stream>>>(W_qk,   WqvX,        DIM_, INNER_);
  transpose_cast_f32<<<dim3(32, 32, 1), tb, 0, stream>>>(W_v,    WqvX + WOFF, DIM_, INNER_);
  transpose_cast_f32<<<dim3(32, 32, 1), tb, 0, stream>>>(W_cqk,  WqvC,        DIM_, INNER_);
  transpose_cast_f32<<<dim3(32, 32, 1), tb, 0, stream>>>(W_cv,   WqvC + WOFF, DIM_, INNER_);
  transpose_cast_f32<<<dim3(32, 32, 1), tb, 0, stream>>>(W_out,  Woutt, INNER_, DIM_);
  transpose_cast_f32<<<dim3(32, 32, 1), tb, 0, stream>>>(W_cout, Wcoutt,INNER_, DIM_);

  // fused QKV: one launch, 4 products, 1024 blocks (4/CU)
  gemm_qkv<<<dim3(2 * INNER_ / 128, (B_ * I_) / 128, 2), 256, 0, stream>>>(
      xn, cn, WqvX, WqvC, qk, vv, ck, cv, B_ * I_, DIM_);

  transpose_bf16<<<dim3(INNER_ / 32, I_ / 32, B_), tb, 0, stream>>>(vv, vT, I_, INNER_);
  transpose_bf16<<<dim3(INNER_ / 32, J_ / 32, B_), tb, 0, stream>>>(cv, cvT, J_, INNER_);

  // stats: both dirs + both b, 64-i tiles, 2048 blocks
  stats_kernel<<<dim3(I_ / 64, H_, 4), 256, 0, stream>>>(qk, ck, rsum, csum, I_, J_);

  const int n4 = (B_ * I_ * INNER_) / 4;
  // dir1: softmax over j, rows i
  fused_attn_kernel<<<(I_ / 32) * 4 * B_, 256, 0, stream>>>(
      qk, ck, cvT, rsum, th_w, p0, p1, p2, p3, I_, J_, J_ / 4);
  reduce_cast_kernel<<<n4 / 256, 256, 0, stream>>>(p0, p1, p2, p3, Oh1, n4);
  // dir2: softmax over i, rows j
  fused_attn_kernel<<<(J_ / 32) * 4 * B_, 256, 0, stream>>>(
      ck, qk, vT, csum, cth_w, p0, p1, p2, p3, J_, I_, I_ / 4);
  reduce_cast_kernel<<<n4 / 256, 256, 0, stream>>>(p0, p1, p2, p3, Oh2, n4);

  // both output GEMMs in one launch (256 blocks)
  gemm_out<<<dim3(DIM_ / 128, (B_ * I_) / 128, 2), 256, 0, stream>>>(
      Oh1, Oh2, Woutt, Wcoutt, b_out, b_cout,
      (float*)d_out, ((float*)d_out) + (size_t)B_ * I_ * DIM_,
      B_ * I_, DIM_, INNER_);
}